// Round 11
// baseline (1881.005 us; speedup 1.0000x reference)
//
#include <hip/hip_runtime.h>
#include <hip/hip_bf16.h>

// B=2, S=2048, W=32, D=1024, H=16, hd=64
// Pipeline (full path):
//   bf16-cast: Wq,Wk,Wv,Wo,q (small only)
//   K GEMM: gemm_big_f32 = round-6 8-phase kk-split fused-cast kernel
//           (405us steady) + DEPTH-2 V-CAST RIDER: rv0/rv1; each odd phase
//           does RST(reg) for the slot loaded 4 PHASES (~9600cyc) earlier
//           (wait provably free; round-10's depth-1 waited on a 1-phase-old
//           load = ~full HBM latency stall per even phase, +110us), then
//           RLD(reg) for a new slot. Slots s=4it+j loaded ph1/3/5/7,
//           stored at slot s+2's phase; 2 tail stores after the loop.
//           Counted-vmcnt soundness: at ph4/ph8-end, 10 ops (2 riders +
//           AISS8) are newer than the B STGs, so vmcnt(8) still drains B;
//           everything it drains is >=2 phases old (free).
//   V GEMM: gemm_big_bf16 = round-0 verified bf16-input kernel (314us).
//   Q/O GEMM: gemm_lds (128x128)
//   attn: per (b,s') head-softmax gather-attention -> A (4096x1024 bf16)
//   out  = A@Wo^T+bo (fp32)

#define DEVI __device__ __forceinline__

typedef __attribute__((ext_vector_type(8))) short bf16x8;
typedef __attribute__((ext_vector_type(4))) float f32x4;
typedef const __attribute__((address_space(1))) void* gvp;
typedef __attribute__((address_space(3))) void* lvp;

DEVI ushort f2bf(float f) {
  uint u = __float_as_uint(f);
  u = u + 0x7fffu + ((u >> 16) & 1u);
  return (ushort)(u >> 16);
}
DEVI float bf2f(ushort u) { return __uint_as_float(((uint)u) << 16); }

// ---------------- elementwise fp32 -> bf16 cast (RNE), 8 elems/thread ----
__global__ __launch_bounds__(256) void cast_kernel(const float* __restrict__ in,
                                                   ushort* __restrict__ out,
                                                   long n) {
  long i = ((long)blockIdx.x * 256 + threadIdx.x) * 8;
  const long stride = (long)gridDim.x * 256 * 8;
  for (; i < n; i += stride) {
    float4 a = *reinterpret_cast<const float4*>(in + i);
    float4 b = *reinterpret_cast<const float4*>(in + i + 4);
    ushort o[8];
    o[0] = f2bf(a.x); o[1] = f2bf(a.y); o[2] = f2bf(a.z); o[3] = f2bf(a.w);
    o[4] = f2bf(b.x); o[5] = f2bf(b.y); o[6] = f2bf(b.z); o[7] = f2bf(b.w);
    *reinterpret_cast<int4*>(out + i) = *reinterpret_cast<const int4*>(o);
  }
}

// ---------------- fused-cast kk-split 8-phase GEMM + depth-2 V rider ------
// C = A(fp32) @ W(bf16)^T + bias, bf16 out. Tile 256x256, BK=64, 16 K-tiles,
// 8 iters x 2 tiles. LDS: buf0 { A@0 (A0,A1), B@32K (B0,B1) }, buf1 = +64K.
// Row = 128B = 8 chunks of 16B; stored chunk p of row r holds source chunk
// p^(r&7); fragment read swz ((kk*4+q)^(lm&7))*16. (= round-6, 405us.)
template <int FJ0>
DEVI void mfma16b(f32x4 (&acc)[8][4], const bf16x8 (&A)[8], const bf16x8 (&B)[2]) {
  __builtin_amdgcn_s_setprio(1);
#pragma unroll
  for (int fi = 0; fi < 8; ++fi)
#pragma unroll
    for (int j = 0; j < 2; ++j)
      acc[fi][FJ0 + j] = __builtin_amdgcn_mfma_f32_16x16x32_bf16(
          A[fi], B[j], acc[fi][FJ0 + j], 0, 0, 0);
  __builtin_amdgcn_s_setprio(0);
}

__global__ __launch_bounds__(512)
__attribute__((amdgpu_waves_per_eu(2, 2)))
void gemm_big_f32(const float* __restrict__ Ag, const ushort* __restrict__ Wg,
                  const float* __restrict__ bias, ushort* __restrict__ Cg,
                  const float* __restrict__ Vsrc, ushort* __restrict__ Vbf) {
  constexpr int K = 1024;
  __shared__ char lds[131072];
  const int tid = threadIdx.x;
  const int lane = tid & 63;
  const int wave = tid >> 6;
  const int wm = wave >> 2;
  const int wn = wave & 3;
  const int d = blockIdx.x;
  const int bn = (d >> 3) & 3;
  const size_t bm = (size_t)(d & 7) * (gridDim.x >> 5) + (d >> 5);

  const ushort* bB = Wg + (size_t)bn * 256 * K;

  const int r0 = tid >> 3;
  const int c0 = (tid & 7) ^ (r0 & 7);
  const float* pR0 = Ag + bm * 256 * K + (size_t)r0 * K + c0 * 8;
  const float* pR1 = pR0 + 64 * K;
  const ushort* bS0 = bB + (size_t)r0 * K + c0 * 8;
  const ushort* bS1 = bB + (size_t)(r0 + 64) * K + c0 * 8;
  const ushort* bS2 = bB + (size_t)(r0 + 128) * K + c0 * 8;
  const ushort* bS3 = bB + (size_t)(r0 + 192) * K + c0 * 8;

  const int lm = lane & 15;
  const int q = lane >> 4;
  const int rowB = lm * 128;
  const int swz0 = (q ^ (lm & 7)) * 16;
  const int swz1 = ((4 + q) ^ (lm & 7)) * 16;
  const char* ldsc = (const char*)lds;
  const char* p0A = ldsc + wm * 16384 + rowB;
  const char* p0B = ldsc + 32768 + (wn >> 1) * 16384 + (wn & 1) * 8192 + rowB;
  const char* p1A = p0A + 65536;
  const char* p1B = p0B + 65536;

  // rider: this block casts v[d*65536 .. d*65536+65535] (fp32 -> bf16)
  const float* rsrc = Vsrc + (size_t)d * 65536 + tid * 4;
  ushort* rdst = Vbf + (size_t)d * 65536 + tid * 4;

  f32x4 acc[8][4] = {};
  bf16x8 A8[8];
  bf16x8 Bf[2];
  float4 st[8];
  float4 rv0, rv1;

#define SB0 __builtin_amdgcn_sched_barrier(0)
#define BAR __builtin_amdgcn_s_barrier()
#define STG(p0, p1, ktE, ldsOff)                                                 \
  {                                                                              \
    __builtin_amdgcn_global_load_lds((gvp)((p0) + (ktE)),                        \
                                     (lvp)(lds + (ldsOff) + tid * 16), 16, 0, 0);\
    __builtin_amdgcn_global_load_lds((gvp)((p1) + (ktE)),                        \
                                     (lvp)(lds + (ldsOff) + 8192 + tid * 16),    \
                                     16, 0, 0);                                  \
  }
#define AISS8(off)                                                      \
  {                                                                     \
    st[0] = *reinterpret_cast<const float4*>(pR0 + (off));              \
    st[1] = *reinterpret_cast<const float4*>(pR0 + (off) + 4);          \
    st[2] = *reinterpret_cast<const float4*>(pR1 + (off));              \
    st[3] = *reinterpret_cast<const float4*>(pR1 + (off) + 4);          \
    st[4] = *reinterpret_cast<const float4*>(pR0 + 131072 + (off));     \
    st[5] = *reinterpret_cast<const float4*>(pR0 + 131072 + (off) + 4); \
    st[6] = *reinterpret_cast<const float4*>(pR1 + 131072 + (off));     \
    st[7] = *reinterpret_cast<const float4*>(pR1 + 131072 + (off) + 4); \
  }
#define CVTPAIR(v0, v1, dstoff)                                              \
  {                                                                          \
    uint w0, w1, w2, w3;                                                     \
    asm("v_cvt_pk_bf16_f32 %0,%1,%2" : "=v"(w0) : "v"((v0).x), "v"((v0).y)); \
    asm("v_cvt_pk_bf16_f32 %0,%1,%2" : "=v"(w1) : "v"((v0).z), "v"((v0).w)); \
    asm("v_cvt_pk_bf16_f32 %0,%1,%2" : "=v"(w2) : "v"((v1).x), "v"((v1).y)); \
    asm("v_cvt_pk_bf16_f32 %0,%1,%2" : "=v"(w3) : "v"((v1).z), "v"((v1).w)); \
    *reinterpret_cast<uint4*>(lds + (dstoff) + tid * 16) =                   \
        make_uint4(w0, w1, w2, w3);                                          \
  }
#define CVT8(base)                          \
  {                                         \
    CVTPAIR(st[0], st[1], (base));          \
    CVTPAIR(st[2], st[3], (base) + 8192);   \
    CVTPAIR(st[4], st[5], (base) + 16384);  \
    CVTPAIR(st[6], st[7], (base) + 24576);  \
  }
#define PH_SYNC()                                    \
  __builtin_amdgcn_s_barrier();                      \
  asm volatile("s_waitcnt lgkmcnt(0)" ::: "memory"); \
  SB0;
#define LDA8(p, swz)                                                       \
  _Pragma("unroll") for (int i_ = 0; i_ < 8; ++i_) {                       \
    A8[i_] = *reinterpret_cast<const bf16x8*>((p) + i_ * 2048 + (swz));    \
  }
#define LDB2(p, fjb, swz)                                                  \
  {                                                                        \
    Bf[0] = *reinterpret_cast<const bf16x8*>((p) + (fjb) + (swz));         \
    Bf[1] = *reinterpret_cast<const bf16x8*>((p) + (fjb) + 2048 + (swz));  \
  }
#define RLD(reg, u) { reg = *reinterpret_cast<const float4*>(rsrc + (size_t)(u) * 2048); }
#define RST(reg, u)                                                            \
  {                                                                            \
    uint w0, w1;                                                               \
    asm("v_cvt_pk_bf16_f32 %0,%1,%2" : "=v"(w0) : "v"(reg.x), "v"(reg.y));     \
    asm("v_cvt_pk_bf16_f32 %0,%1,%2" : "=v"(w1) : "v"(reg.z), "v"(reg.w));     \
    *reinterpret_cast<uint2*>(rdst + (size_t)(u) * 2048) = make_uint2(w0, w1); \
  }

  // ---- prologue: buf0 <- tile0 (A cvt + B stg); leave st = A(1) in flight.
  AISS8(0); SB0;
  CVT8(0);  // auto-wait vmcnt(0); writes buf0.A(tile0)
  SB0;
  STG(bS0, bS1, 0, 32768); STG(bS2, bS3, 0, 49152); SB0;
  AISS8(64); SB0;  // A(1) -> consumed at it0 ph2 CVT
  asm volatile("s_waitcnt vmcnt(8)" ::: "memory");  // drain B(0), keep st
  asm volatile("s_waitcnt lgkmcnt(0)" ::: "memory");
  BAR;
  SB0;

#define ITER(M)                                                           \
  {                                                                       \
    const int ktB1 = (2 * it + 1) * 64;                                   \
    const int ktB2 = (2 * it + 2) * 64;                                   \
    const int ktA2 = (2 * it + 2) * 64;                                   \
    const int ktA3 = (2 * it + 3) * 64;                                   \
    /* ph1: buf0 kk0 fj01; stage BOTH B(j+1) halves -> buf1.B */          \
    LDA8(p0A, swz0); LDB2(p0B, 0, swz0);                                  \
    STG(bS0, bS1, ktB1, 98304); STG(bS2, bS3, ktB1, 114688);              \
    if (it > 0) RST(rv0, it * 4 - 2);                                     \
    RLD(rv0, it * 4 + 0);                                                 \
    PH_SYNC(); mfma16b<0>(acc, A8, Bf); BAR;                              \
    /* ph2: buf0 kk0 fj23; CVT st -> buf1.A(j+1); AISS st <- A(j+2) */    \
    LDB2(p0B, 4096, swz0);                                                \
    CVT8(65536);                                                          \
    SB0;                                                                  \
    if (M == 0) { AISS8(ktA2); SB0; }                                     \
    PH_SYNC(); mfma16b<2>(acc, A8, Bf); BAR;                              \
    /* ph3: buf0 kk1 fj01 */                                              \
    LDA8(p0A, swz1); LDB2(p0B, 0, swz1);                                  \
    if (it > 0) RST(rv1, it * 4 - 1);                                     \
    RLD(rv1, it * 4 + 1);                                                 \
    PH_SYNC(); mfma16b<0>(acc, A8, Bf); BAR;                              \
    /* ph4: buf0 kk1 fj23; end: counted drain for B(j+1) */               \
    LDB2(p0B, 4096, swz1);                                                \
    PH_SYNC(); mfma16b<2>(acc, A8, Bf);                                   \
    SB0;                                                                  \
    if (M == 0) { asm volatile("s_waitcnt vmcnt(8)" ::: "memory"); }      \
    else        { asm volatile("s_waitcnt vmcnt(0)" ::: "memory"); }      \
    BAR; SB0;                                                             \
    /* ph5: buf1 kk0 fj01; stage BOTH B(j+2) halves -> buf0.B */          \
    LDA8(p1A, swz0); LDB2(p1B, 0, swz0);                                  \
    if (M == 0) { STG(bS0, bS1, ktB2, 32768); STG(bS2, bS3, ktB2, 49152); } \
    RST(rv0, it * 4 + 0);                                                 \
    RLD(rv0, it * 4 + 2);                                                 \
    PH_SYNC(); mfma16b<0>(acc, A8, Bf); BAR;                              \
    /* ph6: buf1 kk0 fj23; CVT st -> buf0.A(j+2); AISS st <- A(j+3) */    \
    LDB2(p1B, 4096, swz0);                                                \
    if (M == 0) { CVT8(0); SB0; AISS8(ktA3); SB0; }                       \
    PH_SYNC(); mfma16b<2>(acc, A8, Bf); BAR;                              \
    /* ph7: buf1 kk1 fj01 */                                              \
    LDA8(p1A, swz1); LDB2(p1B, 0, swz1);                                  \
    RST(rv1, it * 4 + 1);                                                 \
    RLD(rv1, it * 4 + 3);                                                 \
    PH_SYNC(); mfma16b<0>(acc, A8, Bf); BAR;                              \
    /* ph8: buf1 kk1 fj23; end: counted drain for B(j+2) */               \
    LDB2(p1B, 4096, swz1);                                                \
    PH_SYNC(); mfma16b<2>(acc, A8, Bf);                                   \
    if (M == 0) {                                                         \
      SB0;                                                                \
      asm volatile("s_waitcnt vmcnt(8)" ::: "memory");                    \
      BAR; SB0;                                                           \
    }                                                                     \
  }

#pragma unroll 1
  for (int it = 0; it < 7; ++it) ITER(0);
  { const int it = 7; ITER(1); }
  // rider tail: slots 30,31 (loaded it7 ph5/ph7)
  RST(rv0, 30);
  RST(rv1, 31);
#undef ITER
#undef STG
#undef AISS8
#undef CVTPAIR
#undef CVT8
#undef PH_SYNC
#undef LDA8
#undef LDB2
#undef RLD
#undef RST
#undef SB0
#undef BAR

  // ---- epilogue: C/D layout col=lane&15, row=(lane>>4)*4+r ----
#pragma unroll
  for (int fi = 0; fi < 8; ++fi) {
#pragma unroll
    for (int fj = 0; fj < 4; ++fj) {
      int n = bn * 256 + wn * 64 + fj * 16 + lm;
      float bv = bias[n];
#pragma unroll
      for (int r = 0; r < 4; ++r) {
        size_t m = bm * 256 + wm * 128 + fi * 16 + ((lane >> 4) * 4) + r;
        Cg[m * 1024 + n] = f2bf(acc[fi][fj][r] + bv);
      }
    }
  }
}

// ---------------- bf16-input deep-pipelined GEMM (round-0, 314us) ---------
// C = A(bf16) @ W(bf16)^T + bias (bf16 out). Tile 256x256, K=1024, BK=32,
// 4-slot LDS ring, depth-3 prefetch, counted vmcnt(8), chunk-XOR swizzle.
__global__ __launch_bounds__(512, 2) void gemm_big_bf16(const ushort* __restrict__ Ag,
                                                        const ushort* __restrict__ Wg,
                                                        const float* __restrict__ bias,
                                                        ushort* __restrict__ Cg) {
  constexpr int K = 1024;
  constexpr int NT = 32;
  constexpr int SLOT = 32768;
  __shared__ char lds[4 * SLOT];
  const int tid = threadIdx.x;
  const int lane = tid & 63;
  const int wave = tid >> 6;
  const int wm = wave >> 2;
  const int wn = wave & 3;
  const int d = blockIdx.x;
  const int bn = (d >> 3) & 3;
  const size_t bm = (size_t)(d & 7) * (gridDim.x >> 5) + (d >> 5);

  const ushort* aB = Ag + bm * 256 * K;
  const ushort* bB = Wg + (size_t)bn * 256 * K;

  const int ar0 = tid >> 2, ac0 = (tid & 3) ^ ((ar0 >> 1) & 3);
  const int ar1 = (tid + 512) >> 2, ac1 = (tid & 3) ^ ((ar1 >> 1) & 3);
  const ushort* aS0 = aB + (size_t)ar0 * K + ac0 * 8;
  const ushort* aS1 = aB + (size_t)ar1 * K + ac1 * 8;
  const ushort* bS0 = bB + (size_t)ar0 * K + ac0 * 8;
  const ushort* bS1 = bB + (size_t)ar1 * K + ac1 * 8;
  const int adst0 = tid * 16;
  const int adst1 = tid * 16 + 8192;
  const int bdst0 = 16384 + tid * 16;
  const int bdst1 = 24576 + tid * 16;

  const int lm = lane & 15;
  const int cs = (lm >> 1) & 3;
  const int cSwz = ((lane >> 4) ^ cs) * 16;
  const int offA = lm * 64 + cSwz + wm * 8192;
  const int offB = 16384 + lm * 64 + cSwz + wn * 4096;

  f32x4 acc[8][4] = {};

#define STAGE_T(slotOff, ktElem)                                                   \
  {                                                                                \
    __builtin_amdgcn_global_load_lds((gvp)(aS0 + (ktElem)),                        \
                                     (lvp)(lds + (slotOff) + adst0), 16, 0, 0);    \
    __builtin_amdgcn_global_load_lds((gvp)(aS1 + (ktElem)),                        \
                                     (lvp)(lds + (slotOff) + adst1), 16, 0, 0);    \
    __builtin_amdgcn_global_load_lds((gvp)(bS0 + (ktElem)),                        \
                                     (lvp)(lds + (slotOff) + bdst0), 16, 0, 0);    \
    __builtin_amdgcn_global_load_lds((gvp)(bS1 + (ktElem)),                        \
                                     (lvp)(lds + (slotOff) + bdst1), 16, 0, 0);    \
  }

  STAGE_T(0 * SLOT, 0);
  STAGE_T(1 * SLOT, 32);
  STAGE_T(2 * SLOT, 64);
  __builtin_amdgcn_sched_barrier(0);
  asm volatile("s_waitcnt vmcnt(8)" ::: "memory");
  __builtin_amdgcn_s_barrier();
  __builtin_amdgcn_sched_barrier(0);

  int rdOff = 0, stOff = 3 * SLOT;
  for (int t = 0; t < NT; ++t) {
    if (t + 3 < NT) STAGE_T(stOff, (t + 3) * 32);
    const char* pA = (const char*)lds + rdOff + offA;
    const char* pB = (const char*)lds + rdOff + offB;
    bf16x8 a[8], b[4];
#pragma unroll
    for (int fi = 0; fi < 8; ++fi)
      a[fi] = *reinterpret_cast<const bf16x8*>(pA + fi * 1024);
#pragma unroll
    for (int fj = 0; fj < 4; ++fj)
      b[fj] = *reinterpret_cast<const bf16x8*>(pB + fj * 1024);
    __builtin_amdgcn_s_setprio(1);
#pragma unroll
    for (int fi = 0; fi < 8; ++fi)
#pragma unroll
      for (int fj = 0; fj < 4; ++fj)
        acc[fi][fj] = __builtin_amdgcn_mfma_f32_16x16x32_bf16(a[fi], b[fj],
                                                              acc[fi][fj], 0, 0, 0);
    __builtin_amdgcn_s_setprio(0);
    if (t < NT - 1) {
      __builtin_amdgcn_sched_barrier(0);
      if (t <= NT - 4)
        asm volatile("s_waitcnt vmcnt(8)" ::: "memory");
      else if (t == NT - 3)
        asm volatile("s_waitcnt vmcnt(4)" ::: "memory");
      else
        asm volatile("s_waitcnt vmcnt(0)" ::: "memory");
      __builtin_amdgcn_s_barrier();
      __builtin_amdgcn_sched_barrier(0);
    }
    rdOff = (rdOff == 3 * SLOT) ? 0 : rdOff + SLOT;
    stOff = (stOff == 3 * SLOT) ? 0 : stOff + SLOT;
  }
#undef STAGE_T

#pragma unroll
  for (int fi = 0; fi < 8; ++fi) {
#pragma unroll
    for (int fj = 0; fj < 4; ++fj) {
      int n = bn * 256 + wn * 64 + fj * 16 + lm;
      float bv = bias[n];
#pragma unroll
      for (int r = 0; r < 4; ++r) {
        size_t m = bm * 256 + wm * 128 + fi * 16 + ((lane >> 4) * 4) + r;
        Cg[m * 1024 + n] = f2bf(acc[fi][fj][r] + bv);
      }
    }
  }
}

// ---------------- 128x128 gload_lds GEMM (Q/O; verified) -------------------
template <typename TOUT>
__global__ __launch_bounds__(256) void gemm_lds(const ushort* __restrict__ Ag,
                                                const ushort* __restrict__ Wg,
                                                const float* __restrict__ bias,
                                                TOUT* __restrict__ Cg) {
  constexpr int K = 1024;
  __shared__ ushort lA[128 * 64];
  __shared__ ushort lB[128 * 64];
  const int tid = threadIdx.x;
  const int lane = tid & 63;
  const int wave = tid >> 6;
  const int wr = (wave >> 1) * 64;
  const int wc = (wave & 1) * 64;
  const int d = blockIdx.x;
  const int bn = (d >> 3) & 7;
  const size_t bm = (size_t)(d & 7) * (gridDim.x >> 6) + (d >> 6);

  const ushort* aB = Ag + bm * 128 * K;
  const ushort* bB = Wg + (size_t)bn * 128 * K;
  const int srow = wave * 32 + (lane >> 3);
  const int scol = ((lane & 7) ^ (lane >> 3)) * 8;
  char* lAc = (char*)lA;
  char* lBc = (char*)lB;

  f32x4 acc[4][4] = {};

  for (int kt = 0; kt < K; kt += 64) {
    __syncthreads();
#pragma unroll
    for (int c = 0; c < 4; ++c) {
      __builtin_amdgcn_global_load_lds(
          (gvp)(aB + (size_t)(srow + c * 8) * K + kt + scol),
          (lvp)(lAc + wave * 4096 + c * 1024), 16, 0, 0);
      __builtin_amdgcn_global_load_lds(
          (gvp)(bB + (size_t)(srow + c * 8) * K + kt + scol),
          (lvp)(lBc + wave * 4096 + c * 1024), 16, 0, 0);
    }
    __syncthreads();
#pragma unroll
    for (int kk = 0; kk < 2; ++kk) {
      bf16x8 af[4], bg[4];
#pragma unroll
      for (int fi = 0; fi < 4; ++fi) {
        int r = wr + fi * 16 + (lane & 15);
        int byte = (r * 128 + kk * 64 + ((lane >> 4) * 16)) ^ ((r & 7) << 4);
        af[fi] = *reinterpret_cast<const bf16x8*>(lAc + byte);
      }
#pragma unroll
      for (int fj = 0; fj < 4; ++fj) {
        int r = wc + fj * 16 + (lane & 15);
        int byte = (r * 128 + kk * 64 + ((lane >> 4) * 16)) ^ ((r & 7) << 4);
        bg[fj] = *reinterpret_cast<const bf16x8*>(lBc + byte);
      }
#pragma unroll
      for (int fi = 0; fi < 4; ++fi)
#pragma unroll
        for (int fj = 0; fj < 4; ++fj)
          acc[fi][fj] = __builtin_amdgcn_mfma_f32_16x16x32_bf16(af[fi], bg[fj],
                                                                acc[fi][fj], 0, 0, 0);
    }
  }
#pragma unroll
  for (int fi = 0; fi < 4; ++fi) {
#pragma unroll
    for (int fj = 0; fj < 4; ++fj) {
      int n = bn * 128 + wc + fj * 16 + (lane & 15);
      float bv = bias[n];
#pragma unroll
      for (int r = 0; r < 4; ++r) {
        size_t m = bm * 128 + wr + fi * 16 + ((lane >> 4) * 4) + r;
        float val = acc[fi][fj][r] + bv;
        if constexpr (sizeof(TOUT) == 2)
          reinterpret_cast<ushort*>(Cg)[m * 1024 + n] = f2bf(val);
        else
          reinterpret_cast<float*>(Cg)[m * 1024 + n] = val;
      }
    }
  }
}

// ------------- reg-staged GEMM (fp32 A): fallback path only ---------------
template <typename TIN, typename TOUT>
__global__ __launch_bounds__(256) void gemm_bias(const TIN* __restrict__ Ag,
                                                 const float* __restrict__ Wg,
                                                 const float* __restrict__ bias,
                                                 TOUT* __restrict__ Cg) {
  constexpr int K = 1024;
  __shared__ char lA[128 * 64 * 2];
  __shared__ char lB[128 * 64 * 2];
  const int tid = threadIdx.x;
  const int lane = tid & 63;
  const int wave = tid >> 6;
  const int wr = (wave >> 1) * 64;
  const int wc = (wave & 1) * 64;
  const int bn = blockIdx.x;
  const size_t bm = blockIdx.y;

  const TIN* aBase = Ag + bm * 128 * K;
  const float* bBase = Wg + (size_t)bn * 128 * K;

  f32x4 acc[4][4] = {};

  for (int kt = 0; kt < K; kt += 64) {
    __syncthreads();
    if constexpr (sizeof(TIN) == 4) {
#pragma unroll
      for (int i = 0; i < 8; ++i) {
        int f = tid + i * 256;
        int row = f >> 4, c4 = f & 15;
        const float4 v = *reinterpret_cast<const float4*>(
            reinterpret_cast<const float*>(aBase) + (size_t)row * K + kt + c4 * 4);
        ushort4 pk;
        pk.x = f2bf(v.x); pk.y = f2bf(v.y); pk.z = f2bf(v.z); pk.w = f2bf(v.w);
        int byte = (row * 128 + c4 * 8) ^ ((row & 7) << 4);
        *reinterpret_cast<ushort4*>(lA + byte) = pk;
      }
    } else {
#pragma unroll
      for (int i = 0; i < 4; ++i) {
        int f = tid + i * 256;
        int row = f >> 3, c8 = f & 7;
        int4 v = *reinterpret_cast<const int4*>(
            reinterpret_cast<const ushort*>(aBase) + (size_t)row * K + kt + c8 * 8);
        int byte = (row * 128 + c8 * 16) ^ ((row & 7) << 4);
        *reinterpret_cast<int4*>(lA + byte) = v;
      }
    }
#pragma unroll
    for (int i = 0; i < 8; ++i) {
      int f = tid + i * 256;
      int row = f >> 4, c4 = f & 15;
      const float4 v =
          *reinterpret_cast<const float4*>(bBase + (size_t)row * K + kt + c4 * 4);
      ushort4 pk;
      pk.x = f2bf(v.x); pk.y = f2bf(v.y); pk.z = f2bf(v.z); pk.w = f2bf(v.w);
      int byte = (row * 128 + c4 * 8) ^ ((row & 7) << 4);
      *reinterpret_cast<ushort4*>(lB + byte) = pk;
    }
    __syncthreads();
#pragma unroll
    for (int kk = 0; kk < 2; ++kk) {
      bf16x8 af[4], bg[4];
#pragma unroll
      for (int fi = 0; fi < 4; ++fi) {
        int r = wr + fi * 16 + (lane & 15);
        int byte = (r * 128 + kk * 64 + ((lane >> 4) * 16)) ^ ((r & 7) << 4);
        af[fi] = *reinterpret_cast<const bf16x8*>(lA + byte);
      }
#pragma unroll
      for (int fj = 0; fj < 4; ++fj) {
        int r = wc + fj * 16 + (lane & 15);
        int byte = (r * 128 + kk * 64 + ((lane >> 4) * 16)) ^ ((r & 7) << 4);
        bg[fj] = *reinterpret_cast<const bf16x8*>(lB + byte);
      }
#pragma unroll
      for (int fi = 0; fi < 4; ++fi)
#pragma unroll
        for (int fj = 0; fj < 4; ++fj)
          acc[fi][fj] =
              __builtin_amdgcn_mfma_f32_16x16x32_bf16(af[fi], bg[fj], acc[fi][fj], 0, 0, 0);
    }
  }
#pragma unroll
  for (int fi = 0; fi < 4; ++fi) {
#pragma unroll
    for (int fj = 0; fj < 4; ++fj) {
      int n = bn * 128 + wc + fj * 16 + (lane & 15);
      float bv = bias[n];
#pragma unroll
      for (int r = 0; r < 4; ++r) {
        size_t m = bm * 128 + wr + fi * 16 + ((lane >> 4) * 4) + r;
        float val = acc[fi][fj][r] + bv;
        if constexpr (sizeof(TOUT) == 2)
          reinterpret_cast<ushort*>(Cg)[m * 1024 + n] = f2bf(val);
        else
          reinterpret_cast<float*>(Cg)[m * 1024 + n] = val;
      }
    }
  }
}

// ---------------- attention: one block per (b,s'), head-axis softmax ------
__global__ __launch_bounds__(512) void attn_kernel(const ushort* __restrict__ Q,
                                                   const ushort* __restrict__ Kl,
                                                   const ushort* __restrict__ Vl,
                                                   ushort* __restrict__ Aout) {
  const int bs = blockIdx.x;
  const int b = bs >> 11, sp = bs & 2047;
  const int tid = threadIdx.x;
  const int wave = tid >> 6, lane = tid & 63;

  __shared__ ushort qrow[1024];
  __shared__ float sc[16][32];
  __shared__ float attnw[16][32];
  __shared__ float mx[32], rinv[32];

  reinterpret_cast<uint*>(qrow)[tid] =
      reinterpret_cast<const uint*>(Q + (size_t)bs * 1024)[tid];
  __syncthreads();

  const int wp = lane & 31, half = lane >> 5;
#pragma unroll
  for (int hh = 0; hh < 2; ++hh) {
    const int h = wave * 2 + hh;
    const int s_k = h * 128 + (sp >> 4);
    const int w_k = (sp & 15) * 2 + (wp >> 4);
    const ushort* kp =
        Kl + (((size_t)(b * 2048 + s_k) * 32) + w_k) * 1024 + (wp & 15) * 64 + half * 32;
    const ushort* qp = qrow + h * 64 + half * 32;
    float dot = 0.f;
#pragma unroll
    for (int j = 0; j < 32; j += 8) {
      int4 kv = *reinterpret_cast<const int4*>(kp + j);
      int4 qv = *reinterpret_cast<const int4*>(qp + j);
      const ushort* ka = reinterpret_cast<const ushort*>(&kv);
      const ushort* qa = reinterpret_cast<const ushort*>(&qv);
#pragma unroll
      for (int t = 0; t < 8; ++t) dot += bf2f(ka[t]) * bf2f(qa[t]);
    }
    dot += __shfl_xor(dot, 32);
    if (half == 0) sc[h][wp] = dot * 0.125f;
  }
  __syncthreads();
  if (tid < 32) {
    float m = sc[0][tid];
#pragma unroll
    for (int h = 1; h < 16; ++h) m = fmaxf(m, sc[h][tid]);
    float s = 0.f;
#pragma unroll
    for (int h = 0; h < 16; ++h) s += __expf(sc[h][tid] - m);
    mx[tid] = m;
    rinv[tid] = 1.f / s;
  }
  __syncthreads();
  if (lane < 32) {
#pragma unroll
    for (int hh = 0; hh < 2; ++hh) {
      const int h = wave * 2 + hh;
      attnw[h][lane] = __expf(sc[h][lane] - mx[lane]) * rinv[lane];
    }
  }
  __syncthreads();
#pragma unroll
  for (int hh = 0; hh < 2; ++hh) {
    const int h = wave * 2 + hh;
    const int s_k = h * 128 + (sp >> 4);
    const size_t vb = (((size_t)(b * 2048 + s_k) * 32) + (sp & 15) * 2) * 1024;
    float a = 0.f;
#pragma unroll
    for (int w2 = 0; w2 < 32; ++w2) {
      float wgt = attnw[h][w2];
      a += wgt * bf2f(Vl[vb + (size_t)(w2 >> 4) * 1024 + (w2 & 15) * 64 + lane]);
    }
    Aout[(((size_t)(b * 16 + h)) * 2048 + sp) * 64 + lane] = f2bf(a);
  }
}

extern "C" void kernel_launch(void* const* d_in, const int* in_sizes, int n_in,
                              void* d_out, int out_size, void* d_ws, size_t ws_size,
                              hipStream_t stream) {
  const float* q = (const float*)d_in[0];
  const float* k = (const float*)d_in[1];
  const float* v = (const float*)d_in[2];
  const float* Wq = (const float*)d_in[3];
  const float* bq = (const float*)d_in[4];
  const float* Wk = (const float*)d_in[5];
  const float* bk = (const float*)d_in[6];
  const float* Wv = (const float*)d_in[7];
  const float* bv = (const float*)d_in[8];
  const float* Wo = (const float*)d_in[9];
  const float* bo = (const float*)d_in[10];
  float* out = (float*)d_out;

  char* ws = (char*)d_ws;
  const size_t MB = 1u << 20;
  ushort* Qlin = (ushort*)ws;                    // 8 MiB
  ushort* Aws  = (ushort*)(ws + 8 * MB);         // 8 MiB
  ushort* wkbf = (ushort*)(ws + 16 * MB);        // 2 MiB
  ushort* wvbf = (ushort*)(ws + 18 * MB);        // 2 MiB
  ushort* wqbf = (ushort*)(ws + 20 * MB);        // 2 MiB
  ushort* wobf = (ushort*)(ws + 22 * MB);        // 2 MiB
  ushort* qbf  = (ushort*)(ws + 24 * MB);        // 8 MiB
  ushort* Klin = (ushort*)(ws + 32 * MB);        // 256 MiB
  ushort* Vlin = (ushort*)(ws + 288 * MB);       // 256 MiB
  ushort* vbf  = (ushort*)(ws + 544 * MB);       // 256 MiB (rider output)
  const bool full = ws_size >= 800 * MB;

  if (full) {
    cast_kernel<<<dim3(512), 256, 0, stream>>>(Wq, wqbf, 1048576L);
    cast_kernel<<<dim3(512), 256, 0, stream>>>(Wk, wkbf, 1048576L);
    cast_kernel<<<dim3(512), 256, 0, stream>>>(Wv, wvbf, 1048576L);
    cast_kernel<<<dim3(512), 256, 0, stream>>>(Wo, wobf, 1048576L);
    cast_kernel<<<dim3(2048), 256, 0, stream>>>(q, qbf, 4194304L);
    gemm_lds<ushort><<<dim3(256), 256, 0, stream>>>(qbf, wqbf, bq, Qlin);
    // K GEMM (fp32 k, fused cast) + depth-2 V-cast rider -> vbf
    gemm_big_f32<<<dim3(2048), 512, 0, stream>>>(k, wkbf, bk, Klin, v, vbf);
    // V GEMM on pre-cast bf16 (round-0 kernel, 314us)
    gemm_big_bf16<<<dim3(2048), 512, 0, stream>>>(vbf, wvbf, bv, Vlin);
    attn_kernel<<<dim3(4096), dim3(512), 0, stream>>>(Qlin, Klin, Vlin, Aws);
    gemm_lds<float><<<dim3(256), 256, 0, stream>>>(Aws, wobf, bo, out);
  } else {
    gemm_bias<float, ushort><<<dim3(8, 32), 256, 0, stream>>>(q, Wq, bq, Qlin);
    gemm_bias<float, ushort><<<dim3(8, 1024), 256, 0, stream>>>(k, Wk, bk, Klin);
    gemm_bias<float, ushort><<<dim3(8, 1024), 256, 0, stream>>>(v, Wv, bv, Vlin);
    attn_kernel<<<dim3(4096), dim3(512), 0, stream>>>(Qlin, Klin, Vlin, Aws);
    gemm_bias<ushort, float><<<dim3(8, 32), 256, 0, stream>>>(Aws, Wo, bo, out);
  }
}

// Round 12
// 1841.848 us; speedup vs baseline: 1.0213x; 1.0213x over previous
//
#include <hip/hip_runtime.h>
#include <hip/hip_bf16.h>

// B=2, S=2048, W=32, D=1024, H=16, hd=64
// Pipeline (full path):
//   bf16-cast: Wq,Wk,Wv,Wo,q (small only)
//   K GEMM: gemm_big_f32 = round-6 8-phase kk-split fused-cast kernel
//           (405us steady) + ZERO-EXTRA-REG V-CAST RIDER: one float4 rv;
//           rider ops ONLY at odd phases: RST(rv, s-1) [consumes the load
//           issued 2 phases (~3800cyc) earlier -> covers congested HBM
//           latency] then RLD(rv, s). Round-10's depth-1-at-every-phase
//           waited on 1-phase-old loads (congested stall, +85us);
//           round-11's depth-2 (+4 VGPR) crossed the hard 128-arch-VGPR
//           cap (256 total budget at 2 waves/EU minus 128 AGPR acc) ->
//           2GB scratch. This variant = round-10 register pressure exactly.
//           vmcnt(8) at ph4/ph8 still drains B: >=10 newer FIFO entries.
//   V GEMM: gemm_big_bf16 = round-0 verified bf16-input kernel (~310us).
//   Q/O GEMM: gemm_lds (128x128)
//   attn: per (b,s') head-softmax gather-attention -> A (4096x1024 bf16)
//   out  = A@Wo^T+bo (fp32)

#define DEVI __device__ __forceinline__

typedef __attribute__((ext_vector_type(8))) short bf16x8;
typedef __attribute__((ext_vector_type(4))) float f32x4;
typedef const __attribute__((address_space(1))) void* gvp;
typedef __attribute__((address_space(3))) void* lvp;

DEVI ushort f2bf(float f) {
  uint u = __float_as_uint(f);
  u = u + 0x7fffu + ((u >> 16) & 1u);
  return (ushort)(u >> 16);
}
DEVI float bf2f(ushort u) { return __uint_as_float(((uint)u) << 16); }

// ---------------- elementwise fp32 -> bf16 cast (RNE), 8 elems/thread ----
__global__ __launch_bounds__(256) void cast_kernel(const float* __restrict__ in,
                                                   ushort* __restrict__ out,
                                                   long n) {
  long i = ((long)blockIdx.x * 256 + threadIdx.x) * 8;
  const long stride = (long)gridDim.x * 256 * 8;
  for (; i < n; i += stride) {
    float4 a = *reinterpret_cast<const float4*>(in + i);
    float4 b = *reinterpret_cast<const float4*>(in + i + 4);
    ushort o[8];
    o[0] = f2bf(a.x); o[1] = f2bf(a.y); o[2] = f2bf(a.z); o[3] = f2bf(a.w);
    o[4] = f2bf(b.x); o[5] = f2bf(b.y); o[6] = f2bf(b.z); o[7] = f2bf(b.w);
    *reinterpret_cast<int4*>(out + i) = *reinterpret_cast<const int4*>(o);
  }
}

// ---------------- fused-cast kk-split 8-phase GEMM + odd-phase V rider ----
// C = A(fp32) @ W(bf16)^T + bias, bf16 out. Tile 256x256, BK=64, 16 K-tiles,
// 8 iters x 2 tiles. LDS: buf0 { A@0 (A0,A1), B@32K (B0,B1) }, buf1 = +64K.
// Row = 128B = 8 chunks of 16B; stored chunk p of row r holds source chunk
// p^(r&7); fragment read swz ((kk*4+q)^(lm&7))*16. (= round-6, 405us.)
template <int FJ0>
DEVI void mfma16b(f32x4 (&acc)[8][4], const bf16x8 (&A)[8], const bf16x8 (&B)[2]) {
  __builtin_amdgcn_s_setprio(1);
#pragma unroll
  for (int fi = 0; fi < 8; ++fi)
#pragma unroll
    for (int j = 0; j < 2; ++j)
      acc[fi][FJ0 + j] = __builtin_amdgcn_mfma_f32_16x16x32_bf16(
          A[fi], B[j], acc[fi][FJ0 + j], 0, 0, 0);
  __builtin_amdgcn_s_setprio(0);
}

__global__ __launch_bounds__(512)
__attribute__((amdgpu_waves_per_eu(2, 2)))
void gemm_big_f32(const float* __restrict__ Ag, const ushort* __restrict__ Wg,
                  const float* __restrict__ bias, ushort* __restrict__ Cg,
                  const float* __restrict__ Vsrc, ushort* __restrict__ Vbf) {
  constexpr int K = 1024;
  __shared__ char lds[131072];
  const int tid = threadIdx.x;
  const int lane = tid & 63;
  const int wave = tid >> 6;
  const int wm = wave >> 2;
  const int wn = wave & 3;
  const int d = blockIdx.x;
  const int bn = (d >> 3) & 3;
  const size_t bm = (size_t)(d & 7) * (gridDim.x >> 5) + (d >> 5);

  const ushort* bB = Wg + (size_t)bn * 256 * K;

  const int r0 = tid >> 3;
  const int c0 = (tid & 7) ^ (r0 & 7);
  const float* pR0 = Ag + bm * 256 * K + (size_t)r0 * K + c0 * 8;
  const float* pR1 = pR0 + 64 * K;
  const ushort* bS0 = bB + (size_t)r0 * K + c0 * 8;
  const ushort* bS1 = bB + (size_t)(r0 + 64) * K + c0 * 8;
  const ushort* bS2 = bB + (size_t)(r0 + 128) * K + c0 * 8;
  const ushort* bS3 = bB + (size_t)(r0 + 192) * K + c0 * 8;

  const int lm = lane & 15;
  const int q = lane >> 4;
  const int rowB = lm * 128;
  const int swz0 = (q ^ (lm & 7)) * 16;
  const int swz1 = ((4 + q) ^ (lm & 7)) * 16;
  const char* ldsc = (const char*)lds;
  const char* p0A = ldsc + wm * 16384 + rowB;
  const char* p0B = ldsc + 32768 + (wn >> 1) * 16384 + (wn & 1) * 8192 + rowB;
  const char* p1A = p0A + 65536;
  const char* p1B = p0B + 65536;

  // rider: this block casts v[d*65536 .. d*65536+65535] (fp32 -> bf16)
  const float* rsrc = Vsrc + (size_t)d * 65536 + tid * 4;
  ushort* rdst = Vbf + (size_t)d * 65536 + tid * 4;

  f32x4 acc[8][4] = {};
  bf16x8 A8[8];
  bf16x8 Bf[2];
  float4 st[8];
  float4 rv;

#define SB0 __builtin_amdgcn_sched_barrier(0)
#define BAR __builtin_amdgcn_s_barrier()
#define STG(p0, p1, ktE, ldsOff)                                                 \
  {                                                                              \
    __builtin_amdgcn_global_load_lds((gvp)((p0) + (ktE)),                        \
                                     (lvp)(lds + (ldsOff) + tid * 16), 16, 0, 0);\
    __builtin_amdgcn_global_load_lds((gvp)((p1) + (ktE)),                        \
                                     (lvp)(lds + (ldsOff) + 8192 + tid * 16),    \
                                     16, 0, 0);                                  \
  }
#define AISS8(off)                                                      \
  {                                                                     \
    st[0] = *reinterpret_cast<const float4*>(pR0 + (off));              \
    st[1] = *reinterpret_cast<const float4*>(pR0 + (off) + 4);          \
    st[2] = *reinterpret_cast<const float4*>(pR1 + (off));              \
    st[3] = *reinterpret_cast<const float4*>(pR1 + (off) + 4);          \
    st[4] = *reinterpret_cast<const float4*>(pR0 + 131072 + (off));     \
    st[5] = *reinterpret_cast<const float4*>(pR0 + 131072 + (off) + 4); \
    st[6] = *reinterpret_cast<const float4*>(pR1 + 131072 + (off));     \
    st[7] = *reinterpret_cast<const float4*>(pR1 + 131072 + (off) + 4); \
  }
#define CVTPAIR(v0, v1, dstoff)                                              \
  {                                                                          \
    uint w0, w1, w2, w3;                                                     \
    asm("v_cvt_pk_bf16_f32 %0,%1,%2" : "=v"(w0) : "v"((v0).x), "v"((v0).y)); \
    asm("v_cvt_pk_bf16_f32 %0,%1,%2" : "=v"(w1) : "v"((v0).z), "v"((v0).w)); \
    asm("v_cvt_pk_bf16_f32 %0,%1,%2" : "=v"(w2) : "v"((v1).x), "v"((v1).y)); \
    asm("v_cvt_pk_bf16_f32 %0,%1,%2" : "=v"(w3) : "v"((v1).z), "v"((v1).w)); \
    *reinterpret_cast<uint4*>(lds + (dstoff) + tid * 16) =                   \
        make_uint4(w0, w1, w2, w3);                                          \
  }
#define CVT8(base)                          \
  {                                         \
    CVTPAIR(st[0], st[1], (base));          \
    CVTPAIR(st[2], st[3], (base) + 8192);   \
    CVTPAIR(st[4], st[5], (base) + 16384);  \
    CVTPAIR(st[6], st[7], (base) + 24576);  \
  }
#define PH_SYNC()                                    \
  __builtin_amdgcn_s_barrier();                      \
  asm volatile("s_waitcnt lgkmcnt(0)" ::: "memory"); \
  SB0;
#define LDA8(p, swz)                                                       \
  _Pragma("unroll") for (int i_ = 0; i_ < 8; ++i_) {                       \
    A8[i_] = *reinterpret_cast<const bf16x8*>((p) + i_ * 2048 + (swz));    \
  }
#define LDB2(p, fjb, swz)                                                  \
  {                                                                        \
    Bf[0] = *reinterpret_cast<const bf16x8*>((p) + (fjb) + (swz));         \
    Bf[1] = *reinterpret_cast<const bf16x8*>((p) + (fjb) + 2048 + (swz));  \
  }
#define RLD(u) { rv = *reinterpret_cast<const float4*>(rsrc + (size_t)(u) * 2048); }
#define RST(u)                                                                 \
  {                                                                            \
    uint w0, w1;                                                               \
    asm("v_cvt_pk_bf16_f32 %0,%1,%2" : "=v"(w0) : "v"(rv.x), "v"(rv.y));       \
    asm("v_cvt_pk_bf16_f32 %0,%1,%2" : "=v"(w1) : "v"(rv.z), "v"(rv.w));       \
    *reinterpret_cast<uint2*>(rdst + (size_t)(u) * 2048) = make_uint2(w0, w1); \
  }

  // ---- prologue: buf0 <- tile0 (A cvt + B stg); leave st = A(1) in flight.
  AISS8(0); SB0;
  CVT8(0);  // auto-wait vmcnt(0); writes buf0.A(tile0)
  SB0;
  STG(bS0, bS1, 0, 32768); STG(bS2, bS3, 0, 49152); SB0;
  AISS8(64); SB0;  // A(1) -> consumed at it0 ph2 CVT
  asm volatile("s_waitcnt vmcnt(8)" ::: "memory");  // drain B(0), keep st
  asm volatile("s_waitcnt lgkmcnt(0)" ::: "memory");
  BAR;
  SB0;

#define ITER(M)                                                           \
  {                                                                       \
    const int ktB1 = (2 * it + 1) * 64;                                   \
    const int ktB2 = (2 * it + 2) * 64;                                   \
    const int ktA2 = (2 * it + 2) * 64;                                   \
    const int ktA3 = (2 * it + 3) * 64;                                   \
    /* ph1: buf0 kk0 fj01; stage BOTH B(j+1) halves -> buf1.B */          \
    LDA8(p0A, swz0); LDB2(p0B, 0, swz0);                                  \
    STG(bS0, bS1, ktB1, 98304); STG(bS2, bS3, ktB1, 114688);              \
    if (it > 0) RST(it * 4 - 1);                                          \
    RLD(it * 4 + 0);                                                      \
    PH_SYNC(); mfma16b<0>(acc, A8, Bf); BAR;                              \
    /* ph2: buf0 kk0 fj23; CVT st -> buf1.A(j+1); AISS st <- A(j+2) */    \
    LDB2(p0B, 4096, swz0);                                                \
    CVT8(65536);                                                          \
    SB0;                                                                  \
    if (M == 0) { AISS8(ktA2); SB0; }                                     \
    PH_SYNC(); mfma16b<2>(acc, A8, Bf); BAR;                              \
    /* ph3: buf0 kk1 fj01; rider: store slot(2 phases old), load next */  \
    LDA8(p0A, swz1); LDB2(p0B, 0, swz1);                                  \
    RST(it * 4 + 0);                                                      \
    RLD(it * 4 + 1);                                                      \
    PH_SYNC(); mfma16b<0>(acc, A8, Bf); BAR;                              \
    /* ph4: buf0 kk1 fj23; end: counted drain for B(j+1) */               \
    LDB2(p0B, 4096, swz1);                                                \
    PH_SYNC(); mfma16b<2>(acc, A8, Bf);                                   \
    SB0;                                                                  \
    if (M == 0) { asm volatile("s_waitcnt vmcnt(8)" ::: "memory"); }      \
    else        { asm volatile("s_waitcnt vmcnt(0)" ::: "memory"); }      \
    BAR; SB0;                                                             \
    /* ph5: buf1 kk0 fj01; stage BOTH B(j+2) halves -> buf0.B */          \
    LDA8(p1A, swz0); LDB2(p1B, 0, swz0);                                  \
    if (M == 0) { STG(bS0, bS1, ktB2, 32768); STG(bS2, bS3, ktB2, 49152); } \
    RST(it * 4 + 1);                                                      \
    RLD(it * 4 + 2);                                                      \
    PH_SYNC(); mfma16b<0>(acc, A8, Bf); BAR;                              \
    /* ph6: buf1 kk0 fj23; CVT st -> buf0.A(j+2); AISS st <- A(j+3) */    \
    LDB2(p1B, 4096, swz0);                                                \
    if (M == 0) { CVT8(0); SB0; AISS8(ktA3); SB0; }                       \
    PH_SYNC(); mfma16b<2>(acc, A8, Bf); BAR;                              \
    /* ph7: buf1 kk1 fj01; rider */                                       \
    LDA8(p1A, swz1); LDB2(p1B, 0, swz1);                                  \
    RST(it * 4 + 2);                                                      \
    RLD(it * 4 + 3);                                                      \
    PH_SYNC(); mfma16b<0>(acc, A8, Bf); BAR;                              \
    /* ph8: buf1 kk1 fj23; end: counted drain for B(j+2) */               \
    LDB2(p1B, 4096, swz1);                                                \
    PH_SYNC(); mfma16b<2>(acc, A8, Bf);                                   \
    if (M == 0) {                                                         \
      SB0;                                                                \
      asm volatile("s_waitcnt vmcnt(8)" ::: "memory");                    \
      BAR; SB0;                                                           \
    }                                                                     \
  }

#pragma unroll 1
  for (int it = 0; it < 7; ++it) ITER(0);
  { const int it = 7; ITER(1); }
  // rider tail: slot 31 (loaded it7 ph7)
  RST(31);
#undef ITER
#undef STG
#undef AISS8
#undef CVTPAIR
#undef CVT8
#undef PH_SYNC
#undef LDA8
#undef LDB2
#undef RLD
#undef RST
#undef SB0
#undef BAR

  // ---- epilogue: C/D layout col=lane&15, row=(lane>>4)*4+r ----
#pragma unroll
  for (int fi = 0; fi < 8; ++fi) {
#pragma unroll
    for (int fj = 0; fj < 4; ++fj) {
      int n = bn * 256 + wn * 64 + fj * 16 + lm;
      float bv = bias[n];
#pragma unroll
      for (int r = 0; r < 4; ++r) {
        size_t m = bm * 256 + wm * 128 + fi * 16 + ((lane >> 4) * 4) + r;
        Cg[m * 1024 + n] = f2bf(acc[fi][fj][r] + bv);
      }
    }
  }
}

// ---------------- bf16-input deep-pipelined GEMM (round-0, 314us) ---------
__global__ __launch_bounds__(512, 2) void gemm_big_bf16(const ushort* __restrict__ Ag,
                                                        const ushort* __restrict__ Wg,
                                                        const float* __restrict__ bias,
                                                        ushort* __restrict__ Cg) {
  constexpr int K = 1024;
  constexpr int NT = 32;
  constexpr int SLOT = 32768;
  __shared__ char lds[4 * SLOT];
  const int tid = threadIdx.x;
  const int lane = tid & 63;
  const int wave = tid >> 6;
  const int wm = wave >> 2;
  const int wn = wave & 3;
  const int d = blockIdx.x;
  const int bn = (d >> 3) & 3;
  const size_t bm = (size_t)(d & 7) * (gridDim.x >> 5) + (d >> 5);

  const ushort* aB = Ag + bm * 256 * K;
  const ushort* bB = Wg + (size_t)bn * 256 * K;

  const int ar0 = tid >> 2, ac0 = (tid & 3) ^ ((ar0 >> 1) & 3);
  const int ar1 = (tid + 512) >> 2, ac1 = (tid & 3) ^ ((ar1 >> 1) & 3);
  const ushort* aS0 = aB + (size_t)ar0 * K + ac0 * 8;
  const ushort* aS1 = aB + (size_t)ar1 * K + ac1 * 8;
  const ushort* bS0 = bB + (size_t)ar0 * K + ac0 * 8;
  const ushort* bS1 = bB + (size_t)ar1 * K + ac1 * 8;
  const int adst0 = tid * 16;
  const int adst1 = tid * 16 + 8192;
  const int bdst0 = 16384 + tid * 16;
  const int bdst1 = 24576 + tid * 16;

  const int lm = lane & 15;
  const int cs = (lm >> 1) & 3;
  const int cSwz = ((lane >> 4) ^ cs) * 16;
  const int offA = lm * 64 + cSwz + wm * 8192;
  const int offB = 16384 + lm * 64 + cSwz + wn * 4096;

  f32x4 acc[8][4] = {};

#define STAGE_T(slotOff, ktElem)                                                   \
  {                                                                                \
    __builtin_amdgcn_global_load_lds((gvp)(aS0 + (ktElem)),                        \
                                     (lvp)(lds + (slotOff) + adst0), 16, 0, 0);    \
    __builtin_amdgcn_global_load_lds((gvp)(aS1 + (ktElem)),                        \
                                     (lvp)(lds + (slotOff) + adst1), 16, 0, 0);    \
    __builtin_amdgcn_global_load_lds((gvp)(bS0 + (ktElem)),                        \
                                     (lvp)(lds + (slotOff) + bdst0), 16, 0, 0);    \
    __builtin_amdgcn_global_load_lds((gvp)(bS1 + (ktElem)),                        \
                                     (lvp)(lds + (slotOff) + bdst1), 16, 0, 0);    \
  }

  STAGE_T(0 * SLOT, 0);
  STAGE_T(1 * SLOT, 32);
  STAGE_T(2 * SLOT, 64);
  __builtin_amdgcn_sched_barrier(0);
  asm volatile("s_waitcnt vmcnt(8)" ::: "memory");
  __builtin_amdgcn_s_barrier();
  __builtin_amdgcn_sched_barrier(0);

  int rdOff = 0, stOff = 3 * SLOT;
  for (int t = 0; t < NT; ++t) {
    if (t + 3 < NT) STAGE_T(stOff, (t + 3) * 32);
    const char* pA = (const char*)lds + rdOff + offA;
    const char* pB = (const char*)lds + rdOff + offB;
    bf16x8 a[8], b[4];
#pragma unroll
    for (int fi = 0; fi < 8; ++fi)
      a[fi] = *reinterpret_cast<const bf16x8*>(pA + fi * 1024);
#pragma unroll
    for (int fj = 0; fj < 4; ++fj)
      b[fj] = *reinterpret_cast<const bf16x8*>(pB + fj * 1024);
    __builtin_amdgcn_s_setprio(1);
#pragma unroll
    for (int fi = 0; fi < 8; ++fi)
#pragma unroll
      for (int fj = 0; fj < 4; ++fj)
        acc[fi][fj] = __builtin_amdgcn_mfma_f32_16x16x32_bf16(a[fi], b[fj],
                                                              acc[fi][fj], 0, 0, 0);
    __builtin_amdgcn_s_setprio(0);
    if (t < NT - 1) {
      __builtin_amdgcn_sched_barrier(0);
      if (t <= NT - 4)
        asm volatile("s_waitcnt vmcnt(8)" ::: "memory");
      else if (t == NT - 3)
        asm volatile("s_waitcnt vmcnt(4)" ::: "memory");
      else
        asm volatile("s_waitcnt vmcnt(0)" ::: "memory");
      __builtin_amdgcn_s_barrier();
      __builtin_amdgcn_sched_barrier(0);
    }
    rdOff = (rdOff == 3 * SLOT) ? 0 : rdOff + SLOT;
    stOff = (stOff == 3 * SLOT) ? 0 : stOff + SLOT;
  }
#undef STAGE_T

#pragma unroll
  for (int fi = 0; fi < 8; ++fi) {
#pragma unroll
    for (int fj = 0; fj < 4; ++fj) {
      int n = bn * 256 + wn * 64 + fj * 16 + lm;
      float bv = bias[n];
#pragma unroll
      for (int r = 0; r < 4; ++r) {
        size_t m = bm * 256 + wm * 128 + fi * 16 + ((lane >> 4) * 4) + r;
        Cg[m * 1024 + n] = f2bf(acc[fi][fj][r] + bv);
      }
    }
  }
}

// ---------------- 128x128 gload_lds GEMM (Q/O; verified) -------------------
template <typename TOUT>
__global__ __launch_bounds__(256) void gemm_lds(const ushort* __restrict__ Ag,
                                                const ushort* __restrict__ Wg,
                                                const float* __restrict__ bias,
                                                TOUT* __restrict__ Cg) {
  constexpr int K = 1024;
  __shared__ ushort lA[128 * 64];
  __shared__ ushort lB[128 * 64];
  const int tid = threadIdx.x;
  const int lane = tid & 63;
  const int wave = tid >> 6;
  const int wr = (wave >> 1) * 64;
  const int wc = (wave & 1) * 64;
  const int d = blockIdx.x;
  const int bn = (d >> 3) & 7;
  const size_t bm = (size_t)(d & 7) * (gridDim.x >> 6) + (d >> 6);

  const ushort* aB = Ag + bm * 128 * K;
  const ushort* bB = Wg + (size_t)bn * 128 * K;
  const int srow = wave * 32 + (lane >> 3);
  const int scol = ((lane & 7) ^ (lane >> 3)) * 8;
  char* lAc = (char*)lA;
  char* lBc = (char*)lB;

  f32x4 acc[4][4] = {};

  for (int kt = 0; kt < K; kt += 64) {
    __syncthreads();
#pragma unroll
    for (int c = 0; c < 4; ++c) {
      __builtin_amdgcn_global_load_lds(
          (gvp)(aB + (size_t)(srow + c * 8) * K + kt + scol),
          (lvp)(lAc + wave * 4096 + c * 1024), 16, 0, 0);
      __builtin_amdgcn_global_load_lds(
          (gvp)(bB + (size_t)(srow + c * 8) * K + kt + scol),
          (lvp)(lBc + wave * 4096 + c * 1024), 16, 0, 0);
    }
    __syncthreads();
#pragma unroll
    for (int kk = 0; kk < 2; ++kk) {
      bf16x8 af[4], bg[4];
#pragma unroll
      for (int fi = 0; fi < 4; ++fi) {
        int r = wr + fi * 16 + (lane & 15);
        int byte = (r * 128 + kk * 64 + ((lane >> 4) * 16)) ^ ((r & 7) << 4);
        af[fi] = *reinterpret_cast<const bf16x8*>(lAc + byte);
      }
#pragma unroll
      for (int fj = 0; fj < 4; ++fj) {
        int r = wc + fj * 16 + (lane & 15);
        int byte = (r * 128 + kk * 64 + ((lane >> 4) * 16)) ^ ((r & 7) << 4);
        bg[fj] = *reinterpret_cast<const bf16x8*>(lBc + byte);
      }
#pragma unroll
      for (int fi = 0; fi < 4; ++fi)
#pragma unroll
        for (int fj = 0; fj < 4; ++fj)
          acc[fi][fj] = __builtin_amdgcn_mfma_f32_16x16x32_bf16(af[fi], bg[fj],
                                                                acc[fi][fj], 0, 0, 0);
    }
  }
#pragma unroll
  for (int fi = 0; fi < 4; ++fi) {
#pragma unroll
    for (int fj = 0; fj < 4; ++fj) {
      int n = bn * 128 + wc + fj * 16 + (lane & 15);
      float bv = bias[n];
#pragma unroll
      for (int r = 0; r < 4; ++r) {
        size_t m = bm * 128 + wr + fi * 16 + ((lane >> 4) * 4) + r;
        float val = acc[fi][fj][r] + bv;
        if constexpr (sizeof(TOUT) == 2)
          reinterpret_cast<ushort*>(Cg)[m * 1024 + n] = f2bf(val);
        else
          reinterpret_cast<float*>(Cg)[m * 1024 + n] = val;
      }
    }
  }
}

// ------------- reg-staged GEMM (fp32 A): fallback path only ---------------
template <typename TIN, typename TOUT>
__global__ __launch_bounds__(256) void gemm_bias(const TIN* __restrict__ Ag,
                                                 const float* __restrict__ Wg,
                                                 const float* __restrict__ bias,
                                                 TOUT* __restrict__ Cg) {
  constexpr int K = 1024;
  __shared__ char lA[128 * 64 * 2];
  __shared__ char lB[128 * 64 * 2];
  const int tid = threadIdx.x;
  const int lane = tid & 63;
  const int wave = tid >> 6;
  const int wr = (wave >> 1) * 64;
  const int wc = (wave & 1) * 64;
  const int bn = blockIdx.x;
  const size_t bm = blockIdx.y;

  const TIN* aBase = Ag + bm * 128 * K;
  const float* bBase = Wg + (size_t)bn * 128 * K;

  f32x4 acc[4][4] = {};

  for (int kt = 0; kt < K; kt += 64) {
    __syncthreads();
    if constexpr (sizeof(TIN) == 4) {
#pragma unroll
      for (int i = 0; i < 8; ++i) {
        int f = tid + i * 256;
        int row = f >> 4, c4 = f & 15;
        const float4 v = *reinterpret_cast<const float4*>(
            reinterpret_cast<const float*>(aBase) + (size_t)row * K + kt + c4 * 4);
        ushort4 pk;
        pk.x = f2bf(v.x); pk.y = f2bf(v.y); pk.z = f2bf(v.z); pk.w = f2bf(v.w);
        int byte = (row * 128 + c4 * 8) ^ ((row & 7) << 4);
        *reinterpret_cast<ushort4*>(lA + byte) = pk;
      }
    } else {
#pragma unroll
      for (int i = 0; i < 4; ++i) {
        int f = tid + i * 256;
        int row = f >> 3, c8 = f & 7;
        int4 v = *reinterpret_cast<const int4*>(
            reinterpret_cast<const ushort*>(aBase) + (size_t)row * K + kt + c8 * 8);
        int byte = (row * 128 + c8 * 16) ^ ((row & 7) << 4);
        *reinterpret_cast<int4*>(lA + byte) = v;
      }
    }
#pragma unroll
    for (int i = 0; i < 8; ++i) {
      int f = tid + i * 256;
      int row = f >> 4, c4 = f & 15;
      const float4 v =
          *reinterpret_cast<const float4*>(bBase + (size_t)row * K + kt + c4 * 4);
      ushort4 pk;
      pk.x = f2bf(v.x); pk.y = f2bf(v.y); pk.z = f2bf(v.z); pk.w = f2bf(v.w);
      int byte = (row * 128 + c4 * 8) ^ ((row & 7) << 4);
      *reinterpret_cast<ushort4*>(lB + byte) = pk;
    }
    __syncthreads();
#pragma unroll
    for (int kk = 0; kk < 2; ++kk) {
      bf16x8 af[4], bg[4];
#pragma unroll
      for (int fi = 0; fi < 4; ++fi) {
        int r = wr + fi * 16 + (lane & 15);
        int byte = (r * 128 + kk * 64 + ((lane >> 4) * 16)) ^ ((r & 7) << 4);
        af[fi] = *reinterpret_cast<const bf16x8*>(lA + byte);
      }
#pragma unroll
      for (int fj = 0; fj < 4; ++fj) {
        int r = wc + fj * 16 + (lane & 15);
        int byte = (r * 128 + kk * 64 + ((lane >> 4) * 16)) ^ ((r & 7) << 4);
        bg[fj] = *reinterpret_cast<const bf16x8*>(lB + byte);
      }
#pragma unroll
      for (int fi = 0; fi < 4; ++fi)
#pragma unroll
        for (int fj = 0; fj < 4; ++fj)
          acc[fi][fj] =
              __builtin_amdgcn_mfma_f32_16x16x32_bf16(af[fi], bg[fj], acc[fi][fj], 0, 0, 0);
    }
  }
#pragma unroll
  for (int fi = 0; fi < 4; ++fi) {
#pragma unroll
    for (int fj = 0; fj < 4; ++fj) {
      int n = bn * 128 + wc + fj * 16 + (lane & 15);
      float bv = bias[n];
#pragma unroll
      for (int r = 0; r < 4; ++r) {
        size_t m = bm * 128 + wr + fi * 16 + ((lane >> 4) * 4) + r;
        float val = acc[fi][fj][r] + bv;
        if constexpr (sizeof(TOUT) == 2)
          reinterpret_cast<ushort*>(Cg)[m * 1024 + n] = f2bf(val);
        else
          reinterpret_cast<float*>(Cg)[m * 1024 + n] = val;
      }
    }
  }
}

// ---------------- attention: one block per (b,s'), head-axis softmax ------
__global__ __launch_bounds__(512) void attn_kernel(const ushort* __restrict__ Q,
                                                   const ushort* __restrict__ Kl,
                                                   const ushort* __restrict__ Vl,
                                                   ushort* __restrict__ Aout) {
  const int bs = blockIdx.x;
  const int b = bs >> 11, sp = bs & 2047;
  const int tid = threadIdx.x;
  const int wave = tid >> 6, lane = tid & 63;

  __shared__ ushort qrow[1024];
  __shared__ float sc[16][32];
  __shared__ float attnw[16][32];
  __shared__ float mx[32], rinv[32];

  reinterpret_cast<uint*>(qrow)[tid] =
      reinterpret_cast<const uint*>(Q + (size_t)bs * 1024)[tid];
  __syncthreads();

  const int wp = lane & 31, half = lane >> 5;
#pragma unroll
  for (int hh = 0; hh < 2; ++hh) {
    const int h = wave * 2 + hh;
    const int s_k = h * 128 + (sp >> 4);
    const int w_k = (sp & 15) * 2 + (wp >> 4);
    const ushort* kp =
        Kl + (((size_t)(b * 2048 + s_k) * 32) + w_k) * 1024 + (wp & 15) * 64 + half * 32;
    const ushort* qp = qrow + h * 64 + half * 32;
    float dot = 0.f;
#pragma unroll
    for (int j = 0; j < 32; j += 8) {
      int4 kv = *reinterpret_cast<const int4*>(kp + j);
      int4 qv = *reinterpret_cast<const int4*>(qp + j);
      const ushort* ka = reinterpret_cast<const ushort*>(&kv);
      const ushort* qa = reinterpret_cast<const ushort*>(&qv);
#pragma unroll
      for (int t = 0; t < 8; ++t) dot += bf2f(ka[t]) * bf2f(qa[t]);
    }
    dot += __shfl_xor(dot, 32);
    if (half == 0) sc[h][wp] = dot * 0.125f;
  }
  __syncthreads();
  if (tid < 32) {
    float m = sc[0][tid];
#pragma unroll
    for (int h = 1; h < 16; ++h) m = fmaxf(m, sc[h][tid]);
    float s = 0.f;
#pragma unroll
    for (int h = 0; h < 16; ++h) s += __expf(sc[h][tid] - m);
    mx[tid] = m;
    rinv[tid] = 1.f / s;
  }
  __syncthreads();
  if (lane < 32) {
#pragma unroll
    for (int hh = 0; hh < 2; ++hh) {
      const int h = wave * 2 + hh;
      attnw[h][lane] = __expf(sc[h][lane] - mx[lane]) * rinv[lane];
    }
  }
  __syncthreads();
#pragma unroll
  for (int hh = 0; hh < 2; ++hh) {
    const int h = wave * 2 + hh;
    const int s_k = h * 128 + (sp >> 4);
    const size_t vb = (((size_t)(b * 2048 + s_k) * 32) + (sp & 15) * 2) * 1024;
    float a = 0.f;
#pragma unroll
    for (int w2 = 0; w2 < 32; ++w2) {
      float wgt = attnw[h][w2];
      a += wgt * bf2f(Vl[vb + (size_t)(w2 >> 4) * 1024 + (w2 & 15) * 64 + lane]);
    }
    Aout[(((size_t)(b * 16 + h)) * 2048 + sp) * 64 + lane] = f2bf(a);
  }
}

extern "C" void kernel_launch(void* const* d_in, const int* in_sizes, int n_in,
                              void* d_out, int out_size, void* d_ws, size_t ws_size,
                              hipStream_t stream) {
  const float* q = (const float*)d_in[0];
  const float* k = (const float*)d_in[1];
  const float* v = (const float*)d_in[2];
  const float* Wq = (const float*)d_in[3];
  const float* bq = (const float*)d_in[4];
  const float* Wk = (const float*)d_in[5];
  const float* bk = (const float*)d_in[6];
  const float* Wv = (const float*)d_in[7];
  const float* bv = (const float*)d_in[8];
  const float* Wo = (const float*)d_in[9];
  const float* bo = (const float*)d_in[10];
  float* out = (float*)d_out;

  char* ws = (char*)d_ws;
  const size_t MB = 1u << 20;
  ushort* Qlin = (ushort*)ws;                    // 8 MiB
  ushort* Aws  = (ushort*)(ws + 8 * MB);         // 8 MiB
  ushort* wkbf = (ushort*)(ws + 16 * MB);        // 2 MiB
  ushort* wvbf = (ushort*)(ws + 18 * MB);        // 2 MiB
  ushort* wqbf = (ushort*)(ws + 20 * MB);        // 2 MiB
  ushort* wobf = (ushort*)(ws + 22 * MB);        // 2 MiB
  ushort* qbf  = (ushort*)(ws + 24 * MB);        // 8 MiB
  ushort* Klin = (ushort*)(ws + 32 * MB);        // 256 MiB
  ushort* Vlin = (ushort*)(ws + 288 * MB);       // 256 MiB
  ushort* vbf  = (ushort*)(ws + 544 * MB);       // 256 MiB (rider output)
  const bool full = ws_size >= 800 * MB;

  if (full) {
    cast_kernel<<<dim3(512), 256, 0, stream>>>(Wq, wqbf, 1048576L);
    cast_kernel<<<dim3(512), 256, 0, stream>>>(Wk, wkbf, 1048576L);
    cast_kernel<<<dim3(512), 256, 0, stream>>>(Wv, wvbf, 1048576L);
    cast_kernel<<<dim3(512), 256, 0, stream>>>(Wo, wobf, 1048576L);
    cast_kernel<<<dim3(2048), 256, 0, stream>>>(q, qbf, 4194304L);
    gemm_lds<ushort><<<dim3(256), 256, 0, stream>>>(qbf, wqbf, bq, Qlin);
    // K GEMM (fp32 k, fused cast) + odd-phase V-cast rider -> vbf
    gemm_big_f32<<<dim3(2048), 512, 0, stream>>>(k, wkbf, bk, Klin, v, vbf);
    // V GEMM on pre-cast bf16 (round-0 kernel)
    gemm_big_bf16<<<dim3(2048), 512, 0, stream>>>(vbf, wvbf, bv, Vlin);
    attn_kernel<<<dim3(4096), dim3(512), 0, stream>>>(Qlin, Klin, Vlin, Aws);
    gemm_lds<float><<<dim3(256), 256, 0, stream>>>(Aws, wobf, bo, out);
  } else {
    gemm_bias<float, ushort><<<dim3(8, 32), 256, 0, stream>>>(q, Wq, bq, Qlin);
    gemm_bias<float, ushort><<<dim3(8, 1024), 256, 0, stream>>>(k, Wk, bk, Klin);
    gemm_bias<float, ushort><<<dim3(8, 1024), 256, 0, stream>>>(v, Wv, bv, Vlin);
    attn_kernel<<<dim3(4096), dim3(512), 0, stream>>>(Qlin, Klin, Vlin, Aws);
    gemm_bias<ushort, float><<<dim3(8, 32), 256, 0, stream>>>(Aws, Wo, bo, out);
  }
}

// Round 13
// 904.302 us; speedup vs baseline: 2.0801x; 2.0368x over previous
//
#include <hip/hip_runtime.h>
#include <hip/hip_bf16.h>

// B=2, S=2048, W=32, D=1024, H=16, hd=64
// Pipeline (full path) — ROUND-6 VERIFIED CONFIG (913.7us) + cast4 merge:
//   bf16-cast: cast4_kernel (Wq,Wk,Wv,Wo in one launch), q (cast_kernel)
//   K/V GEMM: gemm_big = 8-phase kk-split fused fp32->bf16 A-cast kernel
//             (~405us each): tile 256x256, BK=64, LDS 2x64K dbuf,
//             counted vmcnt(8) drains at ph4/ph8 (loads >=2 phases old),
//             one shared A-staging set st[8] (AISS ph2/ph6 -> CVT 4 phases
//             later; intra-iteration liveness only — rounds 10-12 proved
//             ANY extra value live across the loop back-edge spills:
//             acc(128 AGPR) + 128 arch-VGPR cap at 2 waves/EU is exact).
//   Q/O GEMM: gemm_lds (128x128)
//   attn: per (b,s') head-softmax gather-attention -> A (4096x1024 bf16)
//   out  = A@Wo^T+bo (fp32)

#define DEVI __device__ __forceinline__

typedef __attribute__((ext_vector_type(8))) short bf16x8;
typedef __attribute__((ext_vector_type(4))) float f32x4;
typedef const __attribute__((address_space(1))) void* gvp;
typedef __attribute__((address_space(3))) void* lvp;

DEVI ushort f2bf(float f) {
  uint u = __float_as_uint(f);
  u = u + 0x7fffu + ((u >> 16) & 1u);
  return (ushort)(u >> 16);
}
DEVI float bf2f(ushort u) { return __uint_as_float(((uint)u) << 16); }

// ---------------- elementwise fp32 -> bf16 cast (RNE), 8 elems/thread ----
__global__ __launch_bounds__(256) void cast_kernel(const float* __restrict__ in,
                                                   ushort* __restrict__ out,
                                                   long n) {
  long i = ((long)blockIdx.x * 256 + threadIdx.x) * 8;
  const long stride = (long)gridDim.x * 256 * 8;
  for (; i < n; i += stride) {
    float4 a = *reinterpret_cast<const float4*>(in + i);
    float4 b = *reinterpret_cast<const float4*>(in + i + 4);
    ushort o[8];
    o[0] = f2bf(a.x); o[1] = f2bf(a.y); o[2] = f2bf(a.z); o[3] = f2bf(a.w);
    o[4] = f2bf(b.x); o[5] = f2bf(b.y); o[6] = f2bf(b.z); o[7] = f2bf(b.w);
    *reinterpret_cast<int4*>(out + i) = *reinterpret_cast<const int4*>(o);
  }
}

// ---- 4 weight matrices (1M fp32 each) in ONE launch: saves 3 launches ----
__global__ __launch_bounds__(256) void cast4_kernel(const float* __restrict__ i0,
                                                    const float* __restrict__ i1,
                                                    const float* __restrict__ i2,
                                                    const float* __restrict__ i3,
                                                    ushort* __restrict__ o0,
                                                    ushort* __restrict__ o1,
                                                    ushort* __restrict__ o2,
                                                    ushort* __restrict__ o3) {
  const long n = 1048576L;
  long i = ((long)blockIdx.x * 256 + threadIdx.x) * 8;
  const long stride = (long)gridDim.x * 256 * 8;
  for (; i < n; i += stride) {
#pragma unroll
    for (int m = 0; m < 4; ++m) {
      const float* in = (m == 0) ? i0 : (m == 1) ? i1 : (m == 2) ? i2 : i3;
      ushort* out = (m == 0) ? o0 : (m == 1) ? o1 : (m == 2) ? o2 : o3;
      float4 a = *reinterpret_cast<const float4*>(in + i);
      float4 b = *reinterpret_cast<const float4*>(in + i + 4);
      ushort o[8];
      o[0] = f2bf(a.x); o[1] = f2bf(a.y); o[2] = f2bf(a.z); o[3] = f2bf(a.w);
      o[4] = f2bf(b.x); o[5] = f2bf(b.y); o[6] = f2bf(b.z); o[7] = f2bf(b.w);
      *reinterpret_cast<int4*>(out + i) = *reinterpret_cast<const int4*>(o);
    }
  }
}

// ---------------- fused-cast kk-split 8-phase GEMM ------------------------
// C = A(fp32) @ W(bf16)^T + bias, bf16 out. Tile 256x256, BK=64, 16 K-tiles,
// 8 iters x 2 tiles. LDS: buf0 { A@0 (A0,A1), B@32K (B0,B1) }, buf1 = +64K.
// Row = 128B = 8 chunks of 16B; stored chunk p of row r holds source chunk
// p^(r&7); fragment read swz ((kk*4+q)^(lm&7))*16. (round-6 verified, 405us)
template <int FJ0>
DEVI void mfma16b(f32x4 (&acc)[8][4], const bf16x8 (&A)[8], const bf16x8 (&B)[2]) {
  __builtin_amdgcn_s_setprio(1);
#pragma unroll
  for (int fi = 0; fi < 8; ++fi)
#pragma unroll
    for (int j = 0; j < 2; ++j)
      acc[fi][FJ0 + j] = __builtin_amdgcn_mfma_f32_16x16x32_bf16(
          A[fi], B[j], acc[fi][FJ0 + j], 0, 0, 0);
  __builtin_amdgcn_s_setprio(0);
}

__global__ __launch_bounds__(512)
__attribute__((amdgpu_waves_per_eu(2, 2)))
void gemm_big(const float* __restrict__ Ag, const ushort* __restrict__ Wg,
              const float* __restrict__ bias, ushort* __restrict__ Cg) {
  constexpr int K = 1024;
  __shared__ char lds[131072];
  const int tid = threadIdx.x;
  const int lane = tid & 63;
  const int wave = tid >> 6;
  const int wm = wave >> 2;
  const int wn = wave & 3;
  const int d = blockIdx.x;
  const int bn = (d >> 3) & 3;
  const size_t bm = (size_t)(d & 7) * (gridDim.x >> 5) + (d >> 5);

  const ushort* bB = Wg + (size_t)bn * 256 * K;

  const int r0 = tid >> 3;
  const int c0 = (tid & 7) ^ (r0 & 7);
  const float* pR0 = Ag + bm * 256 * K + (size_t)r0 * K + c0 * 8;
  const float* pR1 = pR0 + 64 * K;
  const ushort* bS0 = bB + (size_t)r0 * K + c0 * 8;
  const ushort* bS1 = bB + (size_t)(r0 + 64) * K + c0 * 8;
  const ushort* bS2 = bB + (size_t)(r0 + 128) * K + c0 * 8;
  const ushort* bS3 = bB + (size_t)(r0 + 192) * K + c0 * 8;

  const int lm = lane & 15;
  const int q = lane >> 4;
  const int rowB = lm * 128;
  const int swz0 = (q ^ (lm & 7)) * 16;
  const int swz1 = ((4 + q) ^ (lm & 7)) * 16;
  const char* ldsc = (const char*)lds;
  const char* p0A = ldsc + wm * 16384 + rowB;
  const char* p0B = ldsc + 32768 + (wn >> 1) * 16384 + (wn & 1) * 8192 + rowB;
  const char* p1A = p0A + 65536;
  const char* p1B = p0B + 65536;

  f32x4 acc[8][4] = {};
  bf16x8 A8[8];
  bf16x8 Bf[2];
  float4 st[8];  // single shared staging set (intra-iteration liveness only)

#define SB0 __builtin_amdgcn_sched_barrier(0)
#define BAR __builtin_amdgcn_s_barrier()
#define STG(p0, p1, ktE, ldsOff)                                                 \
  {                                                                              \
    __builtin_amdgcn_global_load_lds((gvp)((p0) + (ktE)),                        \
                                     (lvp)(lds + (ldsOff) + tid * 16), 16, 0, 0);\
    __builtin_amdgcn_global_load_lds((gvp)((p1) + (ktE)),                        \
                                     (lvp)(lds + (ldsOff) + 8192 + tid * 16),    \
                                     16, 0, 0);                                  \
  }
#define AISS8(off)                                                      \
  {                                                                     \
    st[0] = *reinterpret_cast<const float4*>(pR0 + (off));              \
    st[1] = *reinterpret_cast<const float4*>(pR0 + (off) + 4);          \
    st[2] = *reinterpret_cast<const float4*>(pR1 + (off));              \
    st[3] = *reinterpret_cast<const float4*>(pR1 + (off) + 4);          \
    st[4] = *reinterpret_cast<const float4*>(pR0 + 131072 + (off));     \
    st[5] = *reinterpret_cast<const float4*>(pR0 + 131072 + (off) + 4); \
    st[6] = *reinterpret_cast<const float4*>(pR1 + 131072 + (off));     \
    st[7] = *reinterpret_cast<const float4*>(pR1 + 131072 + (off) + 4); \
  }
#define CVTPAIR(v0, v1, dstoff)                                              \
  {                                                                          \
    uint w0, w1, w2, w3;                                                     \
    asm("v_cvt_pk_bf16_f32 %0,%1,%2" : "=v"(w0) : "v"((v0).x), "v"((v0).y)); \
    asm("v_cvt_pk_bf16_f32 %0,%1,%2" : "=v"(w1) : "v"((v0).z), "v"((v0).w)); \
    asm("v_cvt_pk_bf16_f32 %0,%1,%2" : "=v"(w2) : "v"((v1).x), "v"((v1).y)); \
    asm("v_cvt_pk_bf16_f32 %0,%1,%2" : "=v"(w3) : "v"((v1).z), "v"((v1).w)); \
    *reinterpret_cast<uint4*>(lds + (dstoff) + tid * 16) =                   \
        make_uint4(w0, w1, w2, w3);                                          \
  }
#define CVT8(base)                          \
  {                                         \
    CVTPAIR(st[0], st[1], (base));          \
    CVTPAIR(st[2], st[3], (base) + 8192);   \
    CVTPAIR(st[4], st[5], (base) + 16384);  \
    CVTPAIR(st[6], st[7], (base) + 24576);  \
  }
#define PH_SYNC()                                    \
  __builtin_amdgcn_s_barrier();                      \
  asm volatile("s_waitcnt lgkmcnt(0)" ::: "memory"); \
  SB0;
#define LDA8(p, swz)                                                       \
  _Pragma("unroll") for (int i_ = 0; i_ < 8; ++i_) {                       \
    A8[i_] = *reinterpret_cast<const bf16x8*>((p) + i_ * 2048 + (swz));    \
  }
#define LDB2(p, fjb, swz)                                                  \
  {                                                                        \
    Bf[0] = *reinterpret_cast<const bf16x8*>((p) + (fjb) + (swz));         \
    Bf[1] = *reinterpret_cast<const bf16x8*>((p) + (fjb) + 2048 + (swz));  \
  }

  // ---- prologue: buf0 <- tile0 (A cvt + B stg); leave st = A(1) in flight.
  AISS8(0); SB0;
  CVT8(0);  // auto-wait vmcnt(0); writes buf0.A(tile0)
  SB0;
  STG(bS0, bS1, 0, 32768); STG(bS2, bS3, 0, 49152); SB0;
  AISS8(64); SB0;  // A(1) -> consumed at it0 ph2 CVT
  asm volatile("s_waitcnt vmcnt(8)" ::: "memory");  // drain B(0), keep st
  asm volatile("s_waitcnt lgkmcnt(0)" ::: "memory");
  BAR;
  SB0;

#define ITER(M)                                                           \
  {                                                                       \
    const int ktB1 = (2 * it + 1) * 64;                                   \
    const int ktB2 = (2 * it + 2) * 64;                                   \
    const int ktA2 = (2 * it + 2) * 64;                                   \
    const int ktA3 = (2 * it + 3) * 64;                                   \
    /* ph1: buf0 kk0 fj01; stage BOTH B(j+1) halves -> buf1.B */          \
    LDA8(p0A, swz0); LDB2(p0B, 0, swz0);                                  \
    STG(bS0, bS1, ktB1, 98304); STG(bS2, bS3, ktB1, 114688);              \
    PH_SYNC(); mfma16b<0>(acc, A8, Bf); BAR;                              \
    /* ph2: buf0 kk0 fj23; CVT st -> buf1.A(j+1); AISS st <- A(j+2) */    \
    LDB2(p0B, 4096, swz0);                                                \
    CVT8(65536);                                                          \
    SB0;                                                                  \
    if (M == 0) { AISS8(ktA2); SB0; }                                     \
    PH_SYNC(); mfma16b<2>(acc, A8, Bf); BAR;                              \
    /* ph3: buf0 kk1 fj01 */                                              \
    LDA8(p0A, swz1); LDB2(p0B, 0, swz1);                                  \
    PH_SYNC(); mfma16b<0>(acc, A8, Bf); BAR;                              \
    /* ph4: buf0 kk1 fj23; end: counted drain for B(j+1) */               \
    LDB2(p0B, 4096, swz1);                                                \
    PH_SYNC(); mfma16b<2>(acc, A8, Bf);                                   \
    SB0;                                                                  \
    if (M == 0) { asm volatile("s_waitcnt vmcnt(8)" ::: "memory"); }      \
    else        { asm volatile("s_waitcnt vmcnt(0)" ::: "memory"); }      \
    BAR; SB0;                                                             \
    /* ph5: buf1 kk0 fj01; stage BOTH B(j+2) halves -> buf0.B */          \
    LDA8(p1A, swz0); LDB2(p1B, 0, swz0);                                  \
    if (M == 0) { STG(bS0, bS1, ktB2, 32768); STG(bS2, bS3, ktB2, 49152); } \
    PH_SYNC(); mfma16b<0>(acc, A8, Bf); BAR;                              \
    /* ph6: buf1 kk0 fj23; CVT st -> buf0.A(j+2); AISS st <- A(j+3) */    \
    LDB2(p1B, 4096, swz0);                                                \
    if (M == 0) { CVT8(0); SB0; AISS8(ktA3); SB0; }                       \
    PH_SYNC(); mfma16b<2>(acc, A8, Bf); BAR;                              \
    /* ph7: buf1 kk1 fj01 */                                              \
    LDA8(p1A, swz1); LDB2(p1B, 0, swz1);                                  \
    PH_SYNC(); mfma16b<0>(acc, A8, Bf); BAR;                              \
    /* ph8: buf1 kk1 fj23; end: counted drain for B(j+2) */               \
    LDB2(p1B, 4096, swz1);                                                \
    PH_SYNC(); mfma16b<2>(acc, A8, Bf);                                   \
    if (M == 0) {                                                         \
      SB0;                                                                \
      asm volatile("s_waitcnt vmcnt(8)" ::: "memory");                    \
      BAR; SB0;                                                           \
    }                                                                     \
  }

#pragma unroll 1
  for (int it = 0; it < 7; ++it) ITER(0);
  { const int it = 7; ITER(1); }
#undef ITER
#undef STG
#undef AISS8
#undef CVTPAIR
#undef CVT8
#undef PH_SYNC
#undef LDA8
#undef LDB2
#undef SB0
#undef BAR

  // ---- epilogue: C/D layout col=lane&15, row=(lane>>4)*4+r ----
#pragma unroll
  for (int fi = 0; fi < 8; ++fi) {
#pragma unroll
    for (int fj = 0; fj < 4; ++fj) {
      int n = bn * 256 + wn * 64 + fj * 16 + lm;
      float bv = bias[n];
#pragma unroll
      for (int r = 0; r < 4; ++r) {
        size_t m = bm * 256 + wm * 128 + fi * 16 + ((lane >> 4) * 4) + r;
        Cg[m * 1024 + n] = f2bf(acc[fi][fj][r] + bv);
      }
    }
  }
}

// ---------------- 128x128 gload_lds GEMM (Q/O; verified) -------------------
template <typename TOUT>
__global__ __launch_bounds__(256) void gemm_lds(const ushort* __restrict__ Ag,
                                                const ushort* __restrict__ Wg,
                                                const float* __restrict__ bias,
                                                TOUT* __restrict__ Cg) {
  constexpr int K = 1024;
  __shared__ ushort lA[128 * 64];
  __shared__ ushort lB[128 * 64];
  const int tid = threadIdx.x;
  const int lane = tid & 63;
  const int wave = tid >> 6;
  const int wr = (wave >> 1) * 64;
  const int wc = (wave & 1) * 64;
  const int d = blockIdx.x;
  const int bn = (d >> 3) & 7;
  const size_t bm = (size_t)(d & 7) * (gridDim.x >> 6) + (d >> 6);

  const ushort* aB = Ag + bm * 128 * K;
  const ushort* bB = Wg + (size_t)bn * 128 * K;
  const int srow = wave * 32 + (lane >> 3);
  const int scol = ((lane & 7) ^ (lane >> 3)) * 8;
  char* lAc = (char*)lA;
  char* lBc = (char*)lB;

  f32x4 acc[4][4] = {};

  for (int kt = 0; kt < K; kt += 64) {
    __syncthreads();
#pragma unroll
    for (int c = 0; c < 4; ++c) {
      __builtin_amdgcn_global_load_lds(
          (gvp)(aB + (size_t)(srow + c * 8) * K + kt + scol),
          (lvp)(lAc + wave * 4096 + c * 1024), 16, 0, 0);
      __builtin_amdgcn_global_load_lds(
          (gvp)(bB + (size_t)(srow + c * 8) * K + kt + scol),
          (lvp)(lBc + wave * 4096 + c * 1024), 16, 0, 0);
    }
    __syncthreads();
#pragma unroll
    for (int kk = 0; kk < 2; ++kk) {
      bf16x8 af[4], bg[4];
#pragma unroll
      for (int fi = 0; fi < 4; ++fi) {
        int r = wr + fi * 16 + (lane & 15);
        int byte = (r * 128 + kk * 64 + ((lane >> 4) * 16)) ^ ((r & 7) << 4);
        af[fi] = *reinterpret_cast<const bf16x8*>(lAc + byte);
      }
#pragma unroll
      for (int fj = 0; fj < 4; ++fj) {
        int r = wc + fj * 16 + (lane & 15);
        int byte = (r * 128 + kk * 64 + ((lane >> 4) * 16)) ^ ((r & 7) << 4);
        bg[fj] = *reinterpret_cast<const bf16x8*>(lBc + byte);
      }
#pragma unroll
      for (int fi = 0; fi < 4; ++fi)
#pragma unroll
        for (int fj = 0; fj < 4; ++fj)
          acc[fi][fj] = __builtin_amdgcn_mfma_f32_16x16x32_bf16(af[fi], bg[fj],
                                                                acc[fi][fj], 0, 0, 0);
    }
  }
#pragma unroll
  for (int fi = 0; fi < 4; ++fi) {
#pragma unroll
    for (int fj = 0; fj < 4; ++fj) {
      int n = bn * 128 + wc + fj * 16 + (lane & 15);
      float bv = bias[n];
#pragma unroll
      for (int r = 0; r < 4; ++r) {
        size_t m = bm * 128 + wr + fi * 16 + ((lane >> 4) * 4) + r;
        float val = acc[fi][fj][r] + bv;
        if constexpr (sizeof(TOUT) == 2)
          reinterpret_cast<ushort*>(Cg)[m * 1024 + n] = f2bf(val);
        else
          reinterpret_cast<float*>(Cg)[m * 1024 + n] = val;
      }
    }
  }
}

// ------------- reg-staged GEMM (fp32 A): fallback path only ---------------
template <typename TIN, typename TOUT>
__global__ __launch_bounds__(256) void gemm_bias(const TIN* __restrict__ Ag,
                                                 const float* __restrict__ Wg,
                                                 const float* __restrict__ bias,
                                                 TOUT* __restrict__ Cg) {
  constexpr int K = 1024;
  __shared__ char lA[128 * 64 * 2];
  __shared__ char lB[128 * 64 * 2];
  const int tid = threadIdx.x;
  const int lane = tid & 63;
  const int wave = tid >> 6;
  const int wr = (wave >> 1) * 64;
  const int wc = (wave & 1) * 64;
  const int bn = blockIdx.x;
  const size_t bm = blockIdx.y;

  const TIN* aBase = Ag + bm * 128 * K;
  const float* bBase = Wg + (size_t)bn * 128 * K;

  f32x4 acc[4][4] = {};

  for (int kt = 0; kt < K; kt += 64) {
    __syncthreads();
    if constexpr (sizeof(TIN) == 4) {
#pragma unroll
      for (int i = 0; i < 8; ++i) {
        int f = tid + i * 256;
        int row = f >> 4, c4 = f & 15;
        const float4 v = *reinterpret_cast<const float4*>(
            reinterpret_cast<const float*>(aBase) + (size_t)row * K + kt + c4 * 4);
        ushort4 pk;
        pk.x = f2bf(v.x); pk.y = f2bf(v.y); pk.z = f2bf(v.z); pk.w = f2bf(v.w);
        int byte = (row * 128 + c4 * 8) ^ ((row & 7) << 4);
        *reinterpret_cast<ushort4*>(lA + byte) = pk;
      }
    } else {
#pragma unroll
      for (int i = 0; i < 4; ++i) {
        int f = tid + i * 256;
        int row = f >> 3, c8 = f & 7;
        int4 v = *reinterpret_cast<const int4*>(
            reinterpret_cast<const ushort*>(aBase) + (size_t)row * K + kt + c8 * 8);
        int byte = (row * 128 + c8 * 16) ^ ((row & 7) << 4);
        *reinterpret_cast<int4*>(lA + byte) = v;
      }
    }
#pragma unroll
    for (int i = 0; i < 8; ++i) {
      int f = tid + i * 256;
      int row = f >> 4, c4 = f & 15;
      const float4 v =
          *reinterpret_cast<const float4*>(bBase + (size_t)row * K + kt + c4 * 4);
      ushort4 pk;
      pk.x = f2bf(v.x); pk.y = f2bf(v.y); pk.z = f2bf(v.z); pk.w = f2bf(v.w);
      int byte = (row * 128 + c4 * 8) ^ ((row & 7) << 4);
      *reinterpret_cast<ushort4*>(lB + byte) = pk;
    }
    __syncthreads();
#pragma unroll
    for (int kk = 0; kk < 2; ++kk) {
      bf16x8 af[4], bg[4];
#pragma unroll
      for (int fi = 0; fi < 4; ++fi) {
        int r = wr + fi * 16 + (lane & 15);
        int byte = (r * 128 + kk * 64 + ((lane >> 4) * 16)) ^ ((r & 7) << 4);
        af[fi] = *reinterpret_cast<const bf16x8*>(lA + byte);
      }
#pragma unroll
      for (int fj = 0; fj < 4; ++fj) {
        int r = wc + fj * 16 + (lane & 15);
        int byte = (r * 128 + kk * 64 + ((lane >> 4) * 16)) ^ ((r & 7) << 4);
        bg[fj] = *reinterpret_cast<const bf16x8*>(lB + byte);
      }
#pragma unroll
      for (int fi = 0; fi < 4; ++fi)
#pragma unroll
        for (int fj = 0; fj < 4; ++fj)
          acc[fi][fj] =
              __builtin_amdgcn_mfma_f32_16x16x32_bf16(af[fi], bg[fj], acc[fi][fj], 0, 0, 0);
    }
  }
#pragma unroll
  for (int fi = 0; fi < 4; ++fi) {
#pragma unroll
    for (int fj = 0; fj < 4; ++fj) {
      int n = bn * 128 + wc + fj * 16 + (lane & 15);
      float bv = bias[n];
#pragma unroll
      for (int r = 0; r < 4; ++r) {
        size_t m = bm * 128 + wr + fi * 16 + ((lane >> 4) * 4) + r;
        float val = acc[fi][fj][r] + bv;
        if constexpr (sizeof(TOUT) == 2)
          reinterpret_cast<ushort*>(Cg)[m * 1024 + n] = f2bf(val);
        else
          reinterpret_cast<float*>(Cg)[m * 1024 + n] = val;
      }
    }
  }
}

// ---------------- attention: one block per (b,s'), head-axis softmax ------
__global__ __launch_bounds__(512) void attn_kernel(const ushort* __restrict__ Q,
                                                   const ushort* __restrict__ Kl,
                                                   const ushort* __restrict__ Vl,
                                                   ushort* __restrict__ Aout) {
  const int bs = blockIdx.x;
  const int b = bs >> 11, sp = bs & 2047;
  const int tid = threadIdx.x;
  const int wave = tid >> 6, lane = tid & 63;

  __shared__ ushort qrow[1024];
  __shared__ float sc[16][32];
  __shared__ float attnw[16][32];
  __shared__ float mx[32], rinv[32];

  reinterpret_cast<uint*>(qrow)[tid] =
      reinterpret_cast<const uint*>(Q + (size_t)bs * 1024)[tid];
  __syncthreads();

  const int wp = lane & 31, half = lane >> 5;
#pragma unroll
  for (int hh = 0; hh < 2; ++hh) {
    const int h = wave * 2 + hh;
    const int s_k = h * 128 + (sp >> 4);
    const int w_k = (sp & 15) * 2 + (wp >> 4);
    const ushort* kp =
        Kl + (((size_t)(b * 2048 + s_k) * 32) + w_k) * 1024 + (wp & 15) * 64 + half * 32;
    const ushort* qp = qrow + h * 64 + half * 32;
    float dot = 0.f;
#pragma unroll
    for (int j = 0; j < 32; j += 8) {
      int4 kv = *reinterpret_cast<const int4*>(kp + j);
      int4 qv = *reinterpret_cast<const int4*>(qp + j);
      const ushort* ka = reinterpret_cast<const ushort*>(&kv);
      const ushort* qa = reinterpret_cast<const ushort*>(&qv);
#pragma unroll
      for (int t = 0; t < 8; ++t) dot += bf2f(ka[t]) * bf2f(qa[t]);
    }
    dot += __shfl_xor(dot, 32);
    if (half == 0) sc[h][wp] = dot * 0.125f;
  }
  __syncthreads();
  if (tid < 32) {
    float m = sc[0][tid];
#pragma unroll
    for (int h = 1; h < 16; ++h) m = fmaxf(m, sc[h][tid]);
    float s = 0.f;
#pragma unroll
    for (int h = 0; h < 16; ++h) s += __expf(sc[h][tid] - m);
    mx[tid] = m;
    rinv[tid] = 1.f / s;
  }
  __syncthreads();
  if (lane < 32) {
#pragma unroll
    for (int hh = 0; hh < 2; ++hh) {
      const int h = wave * 2 + hh;
      attnw[h][lane] = __expf(sc[h][lane] - mx[lane]) * rinv[lane];
    }
  }
  __syncthreads();
#pragma unroll
  for (int hh = 0; hh < 2; ++hh) {
    const int h = wave * 2 + hh;
    const int s_k = h * 128 + (sp >> 4);
    const size_t vb = (((size_t)(b * 2048 + s_k) * 32) + (sp & 15) * 2) * 1024;
    float a = 0.f;
#pragma unroll
    for (int w2 = 0; w2 < 32; ++w2) {
      float wgt = attnw[h][w2];
      a += wgt * bf2f(Vl[vb + (size_t)(w2 >> 4) * 1024 + (w2 & 15) * 64 + lane]);
    }
    Aout[(((size_t)(b * 16 + h)) * 2048 + sp) * 64 + lane] = f2bf(a);
  }
}

extern "C" void kernel_launch(void* const* d_in, const int* in_sizes, int n_in,
                              void* d_out, int out_size, void* d_ws, size_t ws_size,
                              hipStream_t stream) {
  const float* q = (const float*)d_in[0];
  const float* k = (const float*)d_in[1];
  const float* v = (const float*)d_in[2];
  const float* Wq = (const float*)d_in[3];
  const float* bq = (const float*)d_in[4];
  const float* Wk = (const float*)d_in[5];
  const float* bk = (const float*)d_in[6];
  const float* Wv = (const float*)d_in[7];
  const float* bv = (const float*)d_in[8];
  const float* Wo = (const float*)d_in[9];
  const float* bo = (const float*)d_in[10];
  float* out = (float*)d_out;

  char* ws = (char*)d_ws;
  const size_t MB = 1u << 20;
  ushort* Qlin = (ushort*)ws;                    // 8 MiB
  ushort* Aws  = (ushort*)(ws + 8 * MB);         // 8 MiB
  ushort* wkbf = (ushort*)(ws + 16 * MB);        // 2 MiB
  ushort* wvbf = (ushort*)(ws + 18 * MB);        // 2 MiB
  ushort* wqbf = (ushort*)(ws + 20 * MB);        // 2 MiB
  ushort* wobf = (ushort*)(ws + 22 * MB);        // 2 MiB
  ushort* qbf  = (ushort*)(ws + 24 * MB);        // 8 MiB
  ushort* Klin = (ushort*)(ws + 32 * MB);        // 256 MiB
  ushort* Vlin = (ushort*)(ws + 288 * MB);       // 256 MiB
  const bool full = ws_size >= 800 * MB;

  if (full) {
    cast4_kernel<<<dim3(512), 256, 0, stream>>>(Wq, Wk, Wv, Wo,
                                                wqbf, wkbf, wvbf, wobf);
    cast_kernel<<<dim3(2048), 256, 0, stream>>>(q, qbf, 4194304L);
    gemm_lds<ushort><<<dim3(256), 256, 0, stream>>>(qbf, wqbf, bq, Qlin);
    gemm_big<<<dim3(2048), 512, 0, stream>>>(k, wkbf, bk, Klin);
    gemm_big<<<dim3(2048), 512, 0, stream>>>(v, wvbf, bv, Vlin);
    attn_kernel<<<dim3(4096), dim3(512), 0, stream>>>(Qlin, Klin, Vlin, Aws);
    gemm_lds<float><<<dim3(256), 256, 0, stream>>>(Aws, wobf, bo, out);
  } else {
    gemm_bias<float, ushort><<<dim3(8, 32), 256, 0, stream>>>(q, Wq, bq, Qlin);
    gemm_bias<float, ushort><<<dim3(8, 1024), 256, 0, stream>>>(k, Wk, bk, Klin);
    gemm_bias<float, ushort><<<dim3(8, 1024), 256, 0, stream>>>(v, Wv, bv, Vlin);
    attn_kernel<<<dim3(4096), dim3(512), 0, stream>>>(Qlin, Klin, Vlin, Aws);
    gemm_bias<ushort, float><<<dim3(8, 32), 256, 0, stream>>>(Aws, Wo, bo, out);
  }
}

// Round 14
// 864.792 us; speedup vs baseline: 2.1751x; 1.0457x over previous
//
#include <hip/hip_runtime.h>
#include <hip/hip_bf16.h>

// B=2, S=2048, W=32, D=1024, H=16, hd=64
// Pipeline (full path):
//   bf16-cast: cast4_kernel (Wq,Wk,Wv,Wo in one launch), q (cast_kernel)
//   K/V GEMM: gemm_big = fused fp32->bf16 A-cast kernel, round-14
//             MINIMAL-BARRIER schedule: 4 superphases/iter, only TWO
//             sync points per iter (end-P2, end-P4 = lgkmcnt(0)+vmcnt(8)+
//             s_barrier). Hazard audit (all covered):
//               CVT->buf1.A (P1): prev reads done @ prev-P4-end BAR;
//                 published @ P2-end BAR before P3 reads.
//               STG->buf1.B (P1): published @ P2-end vmcnt(8)+BAR.
//               STG->buf0.B + CVT->buf0.A (P3): P2 reads done @ P2-end BAR;
//                 published @ P4-end vmcnt(8)+BAR.
//               Own frag-reads drained by MFMA auto-waits before barriers.
//             Round-13's 16 barriers/iter were lockstep-only (cycle audit:
//             ~1400 of 1900 cyc/phase was sync tax). Register sets identical
//             to the proven round-6 kernel (128-VGPR cap exact).
//   Q/O GEMM: gemm_lds (128x128)
//   attn: per (b,s') head-softmax gather-attention -> A (4096x1024 bf16)
//   out  = A@Wo^T+bo (fp32)

#define DEVI __device__ __forceinline__

typedef __attribute__((ext_vector_type(8))) short bf16x8;
typedef __attribute__((ext_vector_type(4))) float f32x4;
typedef const __attribute__((address_space(1))) void* gvp;
typedef __attribute__((address_space(3))) void* lvp;

DEVI ushort f2bf(float f) {
  uint u = __float_as_uint(f);
  u = u + 0x7fffu + ((u >> 16) & 1u);
  return (ushort)(u >> 16);
}
DEVI float bf2f(ushort u) { return __uint_as_float(((uint)u) << 16); }

// ---------------- elementwise fp32 -> bf16 cast (RNE), 8 elems/thread ----
__global__ __launch_bounds__(256) void cast_kernel(const float* __restrict__ in,
                                                   ushort* __restrict__ out,
                                                   long n) {
  long i = ((long)blockIdx.x * 256 + threadIdx.x) * 8;
  const long stride = (long)gridDim.x * 256 * 8;
  for (; i < n; i += stride) {
    float4 a = *reinterpret_cast<const float4*>(in + i);
    float4 b = *reinterpret_cast<const float4*>(in + i + 4);
    ushort o[8];
    o[0] = f2bf(a.x); o[1] = f2bf(a.y); o[2] = f2bf(a.z); o[3] = f2bf(a.w);
    o[4] = f2bf(b.x); o[5] = f2bf(b.y); o[6] = f2bf(b.z); o[7] = f2bf(b.w);
    *reinterpret_cast<int4*>(out + i) = *reinterpret_cast<const int4*>(o);
  }
}

// ---- 4 weight matrices (1M fp32 each) in ONE launch: saves 3 launches ----
__global__ __launch_bounds__(256) void cast4_kernel(const float* __restrict__ i0,
                                                    const float* __restrict__ i1,
                                                    const float* __restrict__ i2,
                                                    const float* __restrict__ i3,
                                                    ushort* __restrict__ o0,
                                                    ushort* __restrict__ o1,
                                                    ushort* __restrict__ o2,
                                                    ushort* __restrict__ o3) {
  const long n = 1048576L;
  long i = ((long)blockIdx.x * 256 + threadIdx.x) * 8;
  const long stride = (long)gridDim.x * 256 * 8;
  for (; i < n; i += stride) {
#pragma unroll
    for (int m = 0; m < 4; ++m) {
      const float* in = (m == 0) ? i0 : (m == 1) ? i1 : (m == 2) ? i2 : i3;
      ushort* out = (m == 0) ? o0 : (m == 1) ? o1 : (m == 2) ? o2 : o3;
      float4 a = *reinterpret_cast<const float4*>(in + i);
      float4 b = *reinterpret_cast<const float4*>(in + i + 4);
      ushort o[8];
      o[0] = f2bf(a.x); o[1] = f2bf(a.y); o[2] = f2bf(a.z); o[3] = f2bf(a.w);
      o[4] = f2bf(b.x); o[5] = f2bf(b.y); o[6] = f2bf(b.z); o[7] = f2bf(b.w);
      *reinterpret_cast<int4*>(out + i) = *reinterpret_cast<const int4*>(o);
    }
  }
}

// ---------------- fused-cast minimal-barrier GEMM -------------------------
// C = A(fp32) @ W(bf16)^T + bias, bf16 out. Tile 256x256, BK=64, 16 K-tiles,
// 8 iters x 2 tiles. LDS: buf0 { A@0 (A0,A1), B@32K (B0,B1) }, buf1 = +64K.
// Row = 128B = 8 chunks of 16B; stored chunk p of row r holds source chunk
// p^(r&7); fragment read swz ((kk*4+q)^(lm&7))*16.
// Iter (j=2it):
//  P1: frag buf0 kk0 (fj01+fj23); STG B(j+1)->buf1.B (both halves);
//      CVT st->buf1.A(j+1); AISS st<-A(j+2)
//  P2: frag buf0 kk1; end: lgkmcnt(0)+vmcnt(8)+BAR
//  P3: frag buf1 kk0; STG B(j+2)->buf0.B; CVT st->buf0.A(j+2);
//      AISS st<-A(j+3)
//  P4: frag buf1 kk1; end: lgkmcnt(0)+vmcnt(8)+BAR
// FIFO invariant: enter iter with AISS(8) in flight; CVT auto vmcnt(4)
// (set is half-iter old); P2/P4-end vmcnt(8) drain the 4 STGs exactly.
// Tail it7 (M=1): no AISS, no P3 stages; P2-end vmcnt(0); no P4-end sync.
template <int FJ0>
DEVI void mfma16b(f32x4 (&acc)[8][4], const bf16x8 (&A)[8], const bf16x8 (&B)[2]) {
  __builtin_amdgcn_s_setprio(1);
#pragma unroll
  for (int fi = 0; fi < 8; ++fi)
#pragma unroll
    for (int j = 0; j < 2; ++j)
      acc[fi][FJ0 + j] = __builtin_amdgcn_mfma_f32_16x16x32_bf16(
          A[fi], B[j], acc[fi][FJ0 + j], 0, 0, 0);
  __builtin_amdgcn_s_setprio(0);
}

__global__ __launch_bounds__(512)
__attribute__((amdgpu_waves_per_eu(2, 2)))
void gemm_big(const float* __restrict__ Ag, const ushort* __restrict__ Wg,
              const float* __restrict__ bias, ushort* __restrict__ Cg) {
  constexpr int K = 1024;
  __shared__ char lds[131072];
  const int tid = threadIdx.x;
  const int lane = tid & 63;
  const int wave = tid >> 6;
  const int wm = wave >> 2;
  const int wn = wave & 3;
  const int d = blockIdx.x;
  const int bn = (d >> 3) & 3;
  const size_t bm = (size_t)(d & 7) * (gridDim.x >> 5) + (d >> 5);

  const ushort* bB = Wg + (size_t)bn * 256 * K;

  const int r0 = tid >> 3;
  const int c0 = (tid & 7) ^ (r0 & 7);
  const float* pR0 = Ag + bm * 256 * K + (size_t)r0 * K + c0 * 8;
  const float* pR1 = pR0 + 64 * K;
  const ushort* bS0 = bB + (size_t)r0 * K + c0 * 8;
  const ushort* bS1 = bB + (size_t)(r0 + 64) * K + c0 * 8;
  const ushort* bS2 = bB + (size_t)(r0 + 128) * K + c0 * 8;
  const ushort* bS3 = bB + (size_t)(r0 + 192) * K + c0 * 8;

  const int lm = lane & 15;
  const int q = lane >> 4;
  const int rowB = lm * 128;
  const int swz0 = (q ^ (lm & 7)) * 16;
  const int swz1 = ((4 + q) ^ (lm & 7)) * 16;
  const char* ldsc = (const char*)lds;
  const char* p0A = ldsc + wm * 16384 + rowB;
  const char* p0B = ldsc + 32768 + (wn >> 1) * 16384 + (wn & 1) * 8192 + rowB;
  const char* p1A = p0A + 65536;
  const char* p1B = p0B + 65536;

  f32x4 acc[8][4] = {};
  bf16x8 A8[8];
  bf16x8 Bf[2];
  float4 st[8];  // single shared staging set (intra-iteration liveness only)

#define SB0 __builtin_amdgcn_sched_barrier(0)
#define BAR __builtin_amdgcn_s_barrier()
#define STG(p0, p1, ktE, ldsOff)                                                 \
  {                                                                              \
    __builtin_amdgcn_global_load_lds((gvp)((p0) + (ktE)),                        \
                                     (lvp)(lds + (ldsOff) + tid * 16), 16, 0, 0);\
    __builtin_amdgcn_global_load_lds((gvp)((p1) + (ktE)),                        \
                                     (lvp)(lds + (ldsOff) + 8192 + tid * 16),    \
                                     16, 0, 0);                                  \
  }
#define AISS8(off)                                                      \
  {                                                                     \
    st[0] = *reinterpret_cast<const float4*>(pR0 + (off));              \
    st[1] = *reinterpret_cast<const float4*>(pR0 + (off) + 4);          \
    st[2] = *reinterpret_cast<const float4*>(pR1 + (off));              \
    st[3] = *reinterpret_cast<const float4*>(pR1 + (off) + 4);          \
    st[4] = *reinterpret_cast<const float4*>(pR0 + 131072 + (off));     \
    st[5] = *reinterpret_cast<const float4*>(pR0 + 131072 + (off) + 4); \
    st[6] = *reinterpret_cast<const float4*>(pR1 + 131072 + (off));     \
    st[7] = *reinterpret_cast<const float4*>(pR1 + 131072 + (off) + 4); \
  }
#define CVTPAIR(v0, v1, dstoff)                                              \
  {                                                                          \
    uint w0, w1, w2, w3;                                                     \
    asm("v_cvt_pk_bf16_f32 %0,%1,%2" : "=v"(w0) : "v"((v0).x), "v"((v0).y)); \
    asm("v_cvt_pk_bf16_f32 %0,%1,%2" : "=v"(w1) : "v"((v0).z), "v"((v0).w)); \
    asm("v_cvt_pk_bf16_f32 %0,%1,%2" : "=v"(w2) : "v"((v1).x), "v"((v1).y)); \
    asm("v_cvt_pk_bf16_f32 %0,%1,%2" : "=v"(w3) : "v"((v1).z), "v"((v1).w)); \
    *reinterpret_cast<uint4*>(lds + (dstoff) + tid * 16) =                   \
        make_uint4(w0, w1, w2, w3);                                          \
  }
#define CVT8(base)                          \
  {                                         \
    CVTPAIR(st[0], st[1], (base));          \
    CVTPAIR(st[2], st[3], (base) + 8192);   \
    CVTPAIR(st[4], st[5], (base) + 16384);  \
    CVTPAIR(st[6], st[7], (base) + 24576);  \
  }
#define LDA8(p, swz)                                                       \
  _Pragma("unroll") for (int i_ = 0; i_ < 8; ++i_) {                       \
    A8[i_] = *reinterpret_cast<const bf16x8*>((p) + i_ * 2048 + (swz));    \
  }
#define LDB2(p, fjb, swz)                                                  \
  {                                                                        \
    Bf[0] = *reinterpret_cast<const bf16x8*>((p) + (fjb) + (swz));         \
    Bf[1] = *reinterpret_cast<const bf16x8*>((p) + (fjb) + 2048 + (swz));  \
  }

  // ---- prologue: buf0 <- tile0 (A cvt + B stg); leave st = A(1) in flight.
  AISS8(0); SB0;
  CVT8(0);  // auto-wait vmcnt(0); writes buf0.A(tile0)
  SB0;
  STG(bS0, bS1, 0, 32768); STG(bS2, bS3, 0, 49152); SB0;
  AISS8(64); SB0;  // A(1) -> consumed at it0 P1 CVT
  asm volatile("s_waitcnt vmcnt(8)" ::: "memory");  // drain B(0), keep st
  asm volatile("s_waitcnt lgkmcnt(0)" ::: "memory");
  BAR;
  SB0;

#define ITER(M)                                                           \
  {                                                                       \
    const int ktB1 = (2 * it + 1) * 64;                                   \
    const int ktB2 = (2 * it + 2) * 64;                                   \
    const int ktA2 = (2 * it + 2) * 64;                                   \
    const int ktA3 = (2 * it + 3) * 64;                                   \
    /* P1: buf0 kk0; STG B(j+1)->buf1.B; CVT st->buf1.A(j+1); AISS */     \
    LDA8(p0A, swz0); LDB2(p0B, 0, swz0);                                  \
    STG(bS0, bS1, ktB1, 98304); STG(bS2, bS3, ktB1, 114688);              \
    CVT8(65536);                                                          \
    SB0;                                                                  \
    if (M == 0) { AISS8(ktA2); SB0; }                                     \
    mfma16b<0>(acc, A8, Bf);                                              \
    LDB2(p0B, 4096, swz0);                                                \
    mfma16b<2>(acc, A8, Bf);                                              \
    /* P2: buf0 kk1; end: publish P1 writes */                            \
    LDA8(p0A, swz1); LDB2(p0B, 0, swz1);                                  \
    mfma16b<0>(acc, A8, Bf);                                              \
    LDB2(p0B, 4096, swz1);                                                \
    mfma16b<2>(acc, A8, Bf);                                              \
    SB0;                                                                  \
    asm volatile("s_waitcnt lgkmcnt(0)" ::: "memory");                    \
    if (M == 0) { asm volatile("s_waitcnt vmcnt(8)" ::: "memory"); }      \
    else        { asm volatile("s_waitcnt vmcnt(0)" ::: "memory"); }      \
    BAR; SB0;                                                             \
    /* P3: buf1 kk0; STG B(j+2)->buf0.B; CVT st->buf0.A(j+2); AISS */     \
    LDA8(p1A, swz0); LDB2(p1B, 0, swz0);                                  \
    if (M == 0) {                                                         \
      STG(bS0, bS1, ktB2, 32768); STG(bS2, bS3, ktB2, 49152);             \
      CVT8(0);                                                            \
      SB0;                                                                \
      AISS8(ktA3);                                                        \
      SB0;                                                                \
    }                                                                     \
    mfma16b<0>(acc, A8, Bf);                                              \
    LDB2(p1B, 4096, swz0);                                                \
    mfma16b<2>(acc, A8, Bf);                                              \
    /* P4: buf1 kk1; end: publish P3 writes */                            \
    LDA8(p1A, swz1); LDB2(p1B, 0, swz1);                                  \
    mfma16b<0>(acc, A8, Bf);                                              \
    LDB2(p1B, 4096, swz1);                                                \
    mfma16b<2>(acc, A8, Bf);                                              \
    if (M == 0) {                                                         \
      SB0;                                                                \
      asm volatile("s_waitcnt lgkmcnt(0)" ::: "memory");                  \
      asm volatile("s_waitcnt vmcnt(8)" ::: "memory");                    \
      BAR; SB0;                                                           \
    }                                                                     \
  }

#pragma unroll 1
  for (int it = 0; it < 7; ++it) ITER(0);
  { const int it = 7; ITER(1); }
#undef ITER
#undef STG
#undef AISS8
#undef CVTPAIR
#undef CVT8
#undef LDA8
#undef LDB2
#undef SB0
#undef BAR

  // ---- epilogue: C/D layout col=lane&15, row=(lane>>4)*4+r ----
#pragma unroll
  for (int fi = 0; fi < 8; ++fi) {
#pragma unroll
    for (int fj = 0; fj < 4; ++fj) {
      int n = bn * 256 + wn * 64 + fj * 16 + lm;
      float bv = bias[n];
#pragma unroll
      for (int r = 0; r < 4; ++r) {
        size_t m = bm * 256 + wm * 128 + fi * 16 + ((lane >> 4) * 4) + r;
        Cg[m * 1024 + n] = f2bf(acc[fi][fj][r] + bv);
      }
    }
  }
}

// ---------------- 128x128 gload_lds GEMM (Q/O; verified) -------------------
template <typename TOUT>
__global__ __launch_bounds__(256) void gemm_lds(const ushort* __restrict__ Ag,
                                                const ushort* __restrict__ Wg,
                                                const float* __restrict__ bias,
                                                TOUT* __restrict__ Cg) {
  constexpr int K = 1024;
  __shared__ ushort lA[128 * 64];
  __shared__ ushort lB[128 * 64];
  const int tid = threadIdx.x;
  const int lane = tid & 63;
  const int wave = tid >> 6;
  const int wr = (wave >> 1) * 64;
  const int wc = (wave & 1) * 64;
  const int d = blockIdx.x;
  const int bn = (d >> 3) & 7;
  const size_t bm = (size_t)(d & 7) * (gridDim.x >> 6) + (d >> 6);

  const ushort* aB = Ag + bm * 128 * K;
  const ushort* bB = Wg + (size_t)bn * 128 * K;
  const int srow = wave * 32 + (lane >> 3);
  const int scol = ((lane & 7) ^ (lane >> 3)) * 8;
  char* lAc = (char*)lA;
  char* lBc = (char*)lB;

  f32x4 acc[4][4] = {};

  for (int kt = 0; kt < K; kt += 64) {
    __syncthreads();
#pragma unroll
    for (int c = 0; c < 4; ++c) {
      __builtin_amdgcn_global_load_lds(
          (gvp)(aB + (size_t)(srow + c * 8) * K + kt + scol),
          (lvp)(lAc + wave * 4096 + c * 1024), 16, 0, 0);
      __builtin_amdgcn_global_load_lds(
          (gvp)(bB + (size_t)(srow + c * 8) * K + kt + scol),
          (lvp)(lBc + wave * 4096 + c * 1024), 16, 0, 0);
    }
    __syncthreads();
#pragma unroll
    for (int kk = 0; kk < 2; ++kk) {
      bf16x8 af[4], bg[4];
#pragma unroll
      for (int fi = 0; fi < 4; ++fi) {
        int r = wr + fi * 16 + (lane & 15);
        int byte = (r * 128 + kk * 64 + ((lane >> 4) * 16)) ^ ((r & 7) << 4);
        af[fi] = *reinterpret_cast<const bf16x8*>(lAc + byte);
      }
#pragma unroll
      for (int fj = 0; fj < 4; ++fj) {
        int r = wc + fj * 16 + (lane & 15);
        int byte = (r * 128 + kk * 64 + ((lane >> 4) * 16)) ^ ((r & 7) << 4);
        bg[fj] = *reinterpret_cast<const bf16x8*>(lBc + byte);
      }
#pragma unroll
      for (int fi = 0; fi < 4; ++fi)
#pragma unroll
        for (int fj = 0; fj < 4; ++fj)
          acc[fi][fj] = __builtin_amdgcn_mfma_f32_16x16x32_bf16(af[fi], bg[fj],
                                                                acc[fi][fj], 0, 0, 0);
    }
  }
#pragma unroll
  for (int fi = 0; fi < 4; ++fi) {
#pragma unroll
    for (int fj = 0; fj < 4; ++fj) {
      int n = bn * 128 + wc + fj * 16 + (lane & 15);
      float bv = bias[n];
#pragma unroll
      for (int r = 0; r < 4; ++r) {
        size_t m = bm * 128 + wr + fi * 16 + ((lane >> 4) * 4) + r;
        float val = acc[fi][fj][r] + bv;
        if constexpr (sizeof(TOUT) == 2)
          reinterpret_cast<ushort*>(Cg)[m * 1024 + n] = f2bf(val);
        else
          reinterpret_cast<float*>(Cg)[m * 1024 + n] = val;
      }
    }
  }
}

// ------------- reg-staged GEMM (fp32 A): fallback path only ---------------
template <typename TIN, typename TOUT>
__global__ __launch_bounds__(256) void gemm_bias(const TIN* __restrict__ Ag,
                                                 const float* __restrict__ Wg,
                                                 const float* __restrict__ bias,
                                                 TOUT* __restrict__ Cg) {
  constexpr int K = 1024;
  __shared__ char lA[128 * 64 * 2];
  __shared__ char lB[128 * 64 * 2];
  const int tid = threadIdx.x;
  const int lane = tid & 63;
  const int wave = tid >> 6;
  const int wr = (wave >> 1) * 64;
  const int wc = (wave & 1) * 64;
  const int bn = blockIdx.x;
  const size_t bm = blockIdx.y;

  const TIN* aBase = Ag + bm * 128 * K;
  const float* bBase = Wg + (size_t)bn * 128 * K;

  f32x4 acc[4][4] = {};

  for (int kt = 0; kt < K; kt += 64) {
    __syncthreads();
    if constexpr (sizeof(TIN) == 4) {
#pragma unroll
      for (int i = 0; i < 8; ++i) {
        int f = tid + i * 256;
        int row = f >> 4, c4 = f & 15;
        const float4 v = *reinterpret_cast<const float4*>(
            reinterpret_cast<const float*>(aBase) + (size_t)row * K + kt + c4 * 4);
        ushort4 pk;
        pk.x = f2bf(v.x); pk.y = f2bf(v.y); pk.z = f2bf(v.z); pk.w = f2bf(v.w);
        int byte = (row * 128 + c4 * 8) ^ ((row & 7) << 4);
        *reinterpret_cast<ushort4*>(lA + byte) = pk;
      }
    } else {
#pragma unroll
      for (int i = 0; i < 4; ++i) {
        int f = tid + i * 256;
        int row = f >> 3, c8 = f & 7;
        int4 v = *reinterpret_cast<const int4*>(
            reinterpret_cast<const ushort*>(aBase) + (size_t)row * K + kt + c8 * 8);
        int byte = (row * 128 + c8 * 16) ^ ((row & 7) << 4);
        *reinterpret_cast<int4*>(lA + byte) = v;
      }
    }
#pragma unroll
    for (int i = 0; i < 8; ++i) {
      int f = tid + i * 256;
      int row = f >> 4, c4 = f & 15;
      const float4 v =
          *reinterpret_cast<const float4*>(bBase + (size_t)row * K + kt + c4 * 4);
      ushort4 pk;
      pk.x = f2bf(v.x); pk.y = f2bf(v.y); pk.z = f2bf(v.z); pk.w = f2bf(v.w);
      int byte = (row * 128 + c4 * 8) ^ ((row & 7) << 4);
      *reinterpret_cast<ushort4*>(lB + byte) = pk;
    }
    __syncthreads();
#pragma unroll
    for (int kk = 0; kk < 2; ++kk) {
      bf16x8 af[4], bg[4];
#pragma unroll
      for (int fi = 0; fi < 4; ++fi) {
        int r = wr + fi * 16 + (lane & 15);
        int byte = (r * 128 + kk * 64 + ((lane >> 4) * 16)) ^ ((r & 7) << 4);
        af[fi] = *reinterpret_cast<const bf16x8*>(lA + byte);
      }
#pragma unroll
      for (int fj = 0; fj < 4; ++fj) {
        int r = wc + fj * 16 + (lane & 15);
        int byte = (r * 128 + kk * 64 + ((lane >> 4) * 16)) ^ ((r & 7) << 4);
        bg[fj] = *reinterpret_cast<const bf16x8*>(lB + byte);
      }
#pragma unroll
      for (int fi = 0; fi < 4; ++fi)
#pragma unroll
        for (int fj = 0; fj < 4; ++fj)
          acc[fi][fj] =
              __builtin_amdgcn_mfma_f32_16x16x32_bf16(af[fi], bg[fj], acc[fi][fj], 0, 0, 0);
    }
  }
#pragma unroll
  for (int fi = 0; fi < 4; ++fi) {
#pragma unroll
    for (int fj = 0; fj < 4; ++fj) {
      int n = bn * 128 + wc + fj * 16 + (lane & 15);
      float bv = bias[n];
#pragma unroll
      for (int r = 0; r < 4; ++r) {
        size_t m = bm * 128 + wr + fi * 16 + ((lane >> 4) * 4) + r;
        float val = acc[fi][fj][r] + bv;
        if constexpr (sizeof(TOUT) == 2)
          reinterpret_cast<ushort*>(Cg)[m * 1024 + n] = f2bf(val);
        else
          reinterpret_cast<float*>(Cg)[m * 1024 + n] = val;
      }
    }
  }
}

// ---------------- attention: one block per (b,s'), head-axis softmax ------
__global__ __launch_bounds__(512) void attn_kernel(const ushort* __restrict__ Q,
                                                   const ushort* __restrict__ Kl,
                                                   const ushort* __restrict__ Vl,
                                                   ushort* __restrict__ Aout) {
  const int bs = blockIdx.x;
  const int b = bs >> 11, sp = bs & 2047;
  const int tid = threadIdx.x;
  const int wave = tid >> 6, lane = tid & 63;

  __shared__ ushort qrow[1024];
  __shared__ float sc[16][32];
  __shared__ float attnw[16][32];
  __shared__ float mx[32], rinv[32];

  reinterpret_cast<uint*>(qrow)[tid] =
      reinterpret_cast<const uint*>(Q + (size_t)bs * 1024)[tid];
  __syncthreads();

  const int wp = lane & 31, half = lane >> 5;
#pragma unroll
  for (int hh = 0; hh < 2; ++hh) {
    const int h = wave * 2 + hh;
    const int s_k = h * 128 + (sp >> 4);
    const int w_k = (sp & 15) * 2 + (wp >> 4);
    const ushort* kp =
        Kl + (((size_t)(b * 2048 + s_k) * 32) + w_k) * 1024 + (wp & 15) * 64 + half * 32;
    const ushort* qp = qrow + h * 64 + half * 32;
    float dot = 0.f;
#pragma unroll
    for (int j = 0; j < 32; j += 8) {
      int4 kv = *reinterpret_cast<const int4*>(kp + j);
      int4 qv = *reinterpret_cast<const int4*>(qp + j);
      const ushort* ka = reinterpret_cast<const ushort*>(&kv);
      const ushort* qa = reinterpret_cast<const ushort*>(&qv);
#pragma unroll
      for (int t = 0; t < 8; ++t) dot += bf2f(ka[t]) * bf2f(qa[t]);
    }
    dot += __shfl_xor(dot, 32);
    if (half == 0) sc[h][wp] = dot * 0.125f;
  }
  __syncthreads();
  if (tid < 32) {
    float m = sc[0][tid];
#pragma unroll
    for (int h = 1; h < 16; ++h) m = fmaxf(m, sc[h][tid]);
    float s = 0.f;
#pragma unroll
    for (int h = 0; h < 16; ++h) s += __expf(sc[h][tid] - m);
    mx[tid] = m;
    rinv[tid] = 1.f / s;
  }
  __syncthreads();
  if (lane < 32) {
#pragma unroll
    for (int hh = 0; hh < 2; ++hh) {
      const int h = wave * 2 + hh;
      attnw[h][lane] = __expf(sc[h][lane] - mx[lane]) * rinv[lane];
    }
  }
  __syncthreads();
#pragma unroll
  for (int hh = 0; hh < 2; ++hh) {
    const int h = wave * 2 + hh;
    const int s_k = h * 128 + (sp >> 4);
    const size_t vb = (((size_t)(b * 2048 + s_k) * 32) + (sp & 15) * 2) * 1024;
    float a = 0.f;
#pragma unroll
    for (int w2 = 0; w2 < 32; ++w2) {
      float wgt = attnw[h][w2];
      a += wgt * bf2f(Vl[vb + (size_t)(w2 >> 4) * 1024 + (w2 & 15) * 64 + lane]);
    }
    Aout[(((size_t)(b * 16 + h)) * 2048 + sp) * 64 + lane] = f2bf(a);
  }
}

extern "C" void kernel_launch(void* const* d_in, const int* in_sizes, int n_in,
                              void* d_out, int out_size, void* d_ws, size_t ws_size,
                              hipStream_t stream) {
  const float* q = (const float*)d_in[0];
  const float* k = (const float*)d_in[1];
  const float* v = (const float*)d_in[2];
  const float* Wq = (const float*)d_in[3];
  const float* bq = (const float*)d_in[4];
  const float* Wk = (const float*)d_in[5];
  const float* bk = (const float*)d_in[6];
  const float* Wv = (const float*)d_in[7];
  const float* bv = (const float*)d_in[8];
  const float* Wo = (const float*)d_in[9];
  const float* bo = (const float*)d_in[10];
  float* out = (float*)d_out;

  char* ws = (char*)d_ws;
  const size_t MB = 1u << 20;
  ushort* Qlin = (ushort*)ws;                    // 8 MiB
  ushort* Aws  = (ushort*)(ws + 8 * MB);         // 8 MiB
  ushort* wkbf = (ushort*)(ws + 16 * MB);        // 2 MiB
  ushort* wvbf = (ushort*)(ws + 18 * MB);        // 2 MiB
  ushort* wqbf = (ushort*)(ws + 20 * MB);        // 2 MiB
  ushort* wobf = (ushort*)(ws + 22 * MB);        // 2 MiB
  ushort* qbf  = (ushort*)(ws + 24 * MB);        // 8 MiB
  ushort* Klin = (ushort*)(ws + 32 * MB);        // 256 MiB
  ushort* Vlin = (ushort*)(ws + 288 * MB);       // 256 MiB
  const bool full = ws_size >= 800 * MB;

  if (full) {
    cast4_kernel<<<dim3(512), 256, 0, stream>>>(Wq, Wk, Wv, Wo,
                                                wqbf, wkbf, wvbf, wobf);
    cast_kernel<<<dim3(2048), 256, 0, stream>>>(q, qbf, 4194304L);
    gemm_lds<ushort><<<dim3(256), 256, 0, stream>>>(qbf, wqbf, bq, Qlin);
    gemm_big<<<dim3(2048), 512, 0, stream>>>(k, wkbf, bk, Klin);
    gemm_big<<<dim3(2048), 512, 0, stream>>>(v, wvbf, bv, Vlin);
    attn_kernel<<<dim3(4096), dim3(512), 0, stream>>>(Qlin, Klin, Vlin, Aws);
    gemm_lds<float><<<dim3(256), 256, 0, stream>>>(Aws, wobf, bo, out);
  } else {
    gemm_bias<float, ushort><<<dim3(8, 32), 256, 0, stream>>>(q, Wq, bq, Qlin);
    gemm_bias<float, ushort><<<dim3(8, 1024), 256, 0, stream>>>(k, Wk, bk, Klin);
    gemm_bias<float, ushort><<<dim3(8, 1024), 256, 0, stream>>>(v, Wv, bv, Vlin);
    attn_kernel<<<dim3(4096), dim3(512), 0, stream>>>(Qlin, Klin, Vlin, Aws);
    gemm_bias<ushort, float><<<dim3(8, 32), 256, 0, stream>>>(Aws, Wo, bo, out);
  }
}

// Round 15
// 862.464 us; speedup vs baseline: 2.1810x; 1.0027x over previous
//
#include <hip/hip_runtime.h>
#include <hip/hip_bf16.h>

// B=2, S=2048, W=32, D=1024, H=16, hd=64
// Pipeline (full path):
//   bf16-cast: cast4_kernel (Wq,Wk,Wv,Wo in one launch), q (cast_kernel)
//   K/V GEMM: gemm_big = fused fp32->bf16 A-cast kernel, round-15
//             ZERO-MANUAL-VMCNT schedule: 3-slot B ring (LDS 160K: A dbuf
//             64K @0, B ring 3x32K @64K), B staged 2 tiles ahead. Every STG
//             is drained by an EXISTING CVT auto-wait (CVT@P3 consumes
//             AISS@P1 -> FIFO-drains P1's STGs; next-P1's CVT drains P3's).
//             Sync = 2 x {lgkmcnt(0)+barrier}/iter, nothing else.
//             WAR audit: STG@P3 hits slot of tile j (read P1/P2) - issued
//             after P2-end bar; STG@P1 hits slot of tile j-1 - reads ended
//             at prev-P4-end bar. A-dbuf hazards as round-14 (verified).
//             Registers identical to round-14 (128-cap exact, no spill).
//   Q/O GEMM: gemm_lds (128x128)
//   attn: per (b,s') head-softmax gather-attention -> A (4096x1024 bf16)
//   out  = A@Wo^T+bo (fp32)

#define DEVI __device__ __forceinline__

typedef __attribute__((ext_vector_type(8))) short bf16x8;
typedef __attribute__((ext_vector_type(4))) float f32x4;
typedef const __attribute__((address_space(1))) void* gvp;
typedef __attribute__((address_space(3))) void* lvp;

DEVI ushort f2bf(float f) {
  uint u = __float_as_uint(f);
  u = u + 0x7fffu + ((u >> 16) & 1u);
  return (ushort)(u >> 16);
}
DEVI float bf2f(ushort u) { return __uint_as_float(((uint)u) << 16); }

// ---------------- elementwise fp32 -> bf16 cast (RNE), 8 elems/thread ----
__global__ __launch_bounds__(256) void cast_kernel(const float* __restrict__ in,
                                                   ushort* __restrict__ out,
                                                   long n) {
  long i = ((long)blockIdx.x * 256 + threadIdx.x) * 8;
  const long stride = (long)gridDim.x * 256 * 8;
  for (; i < n; i += stride) {
    float4 a = *reinterpret_cast<const float4*>(in + i);
    float4 b = *reinterpret_cast<const float4*>(in + i + 4);
    ushort o[8];
    o[0] = f2bf(a.x); o[1] = f2bf(a.y); o[2] = f2bf(a.z); o[3] = f2bf(a.w);
    o[4] = f2bf(b.x); o[5] = f2bf(b.y); o[6] = f2bf(b.z); o[7] = f2bf(b.w);
    *reinterpret_cast<int4*>(out + i) = *reinterpret_cast<const int4*>(o);
  }
}

// ---- 4 weight matrices (1M fp32 each) in ONE launch: saves 3 launches ----
__global__ __launch_bounds__(256) void cast4_kernel(const float* __restrict__ i0,
                                                    const float* __restrict__ i1,
                                                    const float* __restrict__ i2,
                                                    const float* __restrict__ i3,
                                                    ushort* __restrict__ o0,
                                                    ushort* __restrict__ o1,
                                                    ushort* __restrict__ o2,
                                                    ushort* __restrict__ o3) {
  const long n = 1048576L;
  long i = ((long)blockIdx.x * 256 + threadIdx.x) * 8;
  const long stride = (long)gridDim.x * 256 * 8;
  for (; i < n; i += stride) {
#pragma unroll
    for (int m = 0; m < 4; ++m) {
      const float* in = (m == 0) ? i0 : (m == 1) ? i1 : (m == 2) ? i2 : i3;
      ushort* out = (m == 0) ? o0 : (m == 1) ? o1 : (m == 2) ? o2 : o3;
      float4 a = *reinterpret_cast<const float4*>(in + i);
      float4 b = *reinterpret_cast<const float4*>(in + i + 4);
      ushort o[8];
      o[0] = f2bf(a.x); o[1] = f2bf(a.y); o[2] = f2bf(a.z); o[3] = f2bf(a.w);
      o[4] = f2bf(b.x); o[5] = f2bf(b.y); o[6] = f2bf(b.z); o[7] = f2bf(b.w);
      *reinterpret_cast<int4*>(out + i) = *reinterpret_cast<const int4*>(o);
    }
  }
}

// ---------------- fused-cast B-ring-3 GEMM --------------------------------
// C = A(fp32) @ W(bf16)^T + bias, bf16 out. Tile 256x256, BK=64, 16 K-tiles,
// 8 iters x 2 tiles. LDS 160K: buf0.A @0 (32K), buf1.A @32K, B ring slots
// 0/1/2 @ 64K+s*32K. Row = 128B = 8 chunks of 16B; stored chunk p of row r
// holds source chunk p^(r&7); fragment read swz ((kk*4+q)^(lm&7))*16.
// Iter it (tiles j=2it,j+1; read slots RA=j%3, RB=(j+1)%3; stage SC=(j+2)%3,
// SD=(j+3)%3):
//  P1: frag buf0.A/B[RA] kk0; STG B(j+2)->SC; CVT st->buf1.A(j+1); AISS A(j+2)
//  P2: kk1;                 end: lgkmcnt(0)+BAR
//  P3: frag buf1.A/B[RB] kk0; STG B(j+3)->SD; CVT st->buf0.A(j+2); AISS A(j+3)
//  P4: kk1;                 end: lgkmcnt(0)+BAR
// Drains: CVT@P1 auto-drains prev-P3 STG+AISS; CVT@P3 auto-drains P1
// STG+AISS. No manual vmcnt in loop. Tail it7 (M=1): CVT@P1 only.
template <int FJ0>
DEVI void mfma16b(f32x4 (&acc)[8][4], const bf16x8 (&A)[8], const bf16x8 (&B)[2]) {
  __builtin_amdgcn_s_setprio(1);
#pragma unroll
  for (int fi = 0; fi < 8; ++fi)
#pragma unroll
    for (int j = 0; j < 2; ++j)
      acc[fi][FJ0 + j] = __builtin_amdgcn_mfma_f32_16x16x32_bf16(
          A[fi], B[j], acc[fi][FJ0 + j], 0, 0, 0);
  __builtin_amdgcn_s_setprio(0);
}

__global__ __launch_bounds__(512)
__attribute__((amdgpu_waves_per_eu(2, 2)))
void gemm_big(const float* __restrict__ Ag, const ushort* __restrict__ Wg,
              const float* __restrict__ bias, ushort* __restrict__ Cg) {
  constexpr int K = 1024;
  __shared__ char lds[163840];
  const int tid = threadIdx.x;
  const int lane = tid & 63;
  const int wave = tid >> 6;
  const int wm = wave >> 2;
  const int wn = wave & 3;
  const int d = blockIdx.x;
  const int bn = (d >> 3) & 3;
  const size_t bm = (size_t)(d & 7) * (gridDim.x >> 5) + (d >> 5);

  const ushort* bB = Wg + (size_t)bn * 256 * K;

  const int r0 = tid >> 3;
  const int c0 = (tid & 7) ^ (r0 & 7);
  const float* pR0 = Ag + bm * 256 * K + (size_t)r0 * K + c0 * 8;
  const float* pR1 = pR0 + 64 * K;
  const ushort* bS0 = bB + (size_t)r0 * K + c0 * 8;
  const ushort* bS1 = bB + (size_t)(r0 + 64) * K + c0 * 8;
  const ushort* bS2 = bB + (size_t)(r0 + 128) * K + c0 * 8;
  const ushort* bS3 = bB + (size_t)(r0 + 192) * K + c0 * 8;

  const int lm = lane & 15;
  const int q = lane >> 4;
  const int rowB = lm * 128;
  const int swz0 = (q ^ (lm & 7)) * 16;
  const int swz1 = ((4 + q) ^ (lm & 7)) * 16;
  const char* ldsc = (const char*)lds;
  const char* p0A = ldsc + wm * 16384 + rowB;
  const char* p1A = p0A + 32768;
  const int bOff = (wn >> 1) * 16384 + (wn & 1) * 8192 + rowB;

  f32x4 acc[8][4] = {};
  bf16x8 A8[8];
  bf16x8 Bf[2];
  float4 st[8];  // single shared staging set (intra-iteration liveness only)

#define SB0 __builtin_amdgcn_sched_barrier(0)
#define BAR __builtin_amdgcn_s_barrier()
#define STG(p0, p1, ktE, ldsOff)                                                 \
  {                                                                              \
    __builtin_amdgcn_global_load_lds((gvp)((p0) + (ktE)),                        \
                                     (lvp)(lds + (ldsOff) + tid * 16), 16, 0, 0);\
    __builtin_amdgcn_global_load_lds((gvp)((p1) + (ktE)),                        \
                                     (lvp)(lds + (ldsOff) + 8192 + tid * 16),    \
                                     16, 0, 0);                                  \
  }
#define AISS8(off)                                                      \
  {                                                                     \
    st[0] = *reinterpret_cast<const float4*>(pR0 + (off));              \
    st[1] = *reinterpret_cast<const float4*>(pR0 + (off) + 4);          \
    st[2] = *reinterpret_cast<const float4*>(pR1 + (off));              \
    st[3] = *reinterpret_cast<const float4*>(pR1 + (off) + 4);          \
    st[4] = *reinterpret_cast<const float4*>(pR0 + 131072 + (off));     \
    st[5] = *reinterpret_cast<const float4*>(pR0 + 131072 + (off) + 4); \
    st[6] = *reinterpret_cast<const float4*>(pR1 + 131072 + (off));     \
    st[7] = *reinterpret_cast<const float4*>(pR1 + 131072 + (off) + 4); \
  }
#define CVTPAIR(v0, v1, dstoff)                                              \
  {                                                                          \
    uint w0, w1, w2, w3;                                                     \
    asm("v_cvt_pk_bf16_f32 %0,%1,%2" : "=v"(w0) : "v"((v0).x), "v"((v0).y)); \
    asm("v_cvt_pk_bf16_f32 %0,%1,%2" : "=v"(w1) : "v"((v0).z), "v"((v0).w)); \
    asm("v_cvt_pk_bf16_f32 %0,%1,%2" : "=v"(w2) : "v"((v1).x), "v"((v1).y)); \
    asm("v_cvt_pk_bf16_f32 %0,%1,%2" : "=v"(w3) : "v"((v1).z), "v"((v1).w)); \
    *reinterpret_cast<uint4*>(lds + (dstoff) + tid * 16) =                   \
        make_uint4(w0, w1, w2, w3);                                          \
  }
#define CVT8(base)                          \
  {                                         \
    CVTPAIR(st[0], st[1], (base));          \
    CVTPAIR(st[2], st[3], (base) + 8192);   \
    CVTPAIR(st[4], st[5], (base) + 16384);  \
    CVTPAIR(st[6], st[7], (base) + 24576);  \
  }
#define LDA8(p, swz)                                                       \
  _Pragma("unroll") for (int i_ = 0; i_ < 8; ++i_) {                       \
    A8[i_] = *reinterpret_cast<const bf16x8*>((p) + i_ * 2048 + (swz));    \
  }
#define LDB2(p, fjb, swz)                                                  \
  {                                                                        \
    Bf[0] = *reinterpret_cast<const bf16x8*>((p) + (fjb) + (swz));         \
    Bf[1] = *reinterpret_cast<const bf16x8*>((p) + (fjb) + 2048 + (swz));  \
  }

  // ---- prologue: A(0) cvt -> buf0.A; B(0)->slot0, B(1)->slot1;
  // AISS A(1) left in flight (drained by it0-P1's CVT).
  AISS8(0); SB0;
  CVT8(0);  // auto-drain; writes buf0.A(0)
  SB0;
  STG(bS0, bS1, 0, 65536); STG(bS2, bS3, 0, 65536 + 16384); SB0;
  STG(bS0, bS1, 64, 98304); STG(bS2, bS3, 64, 98304 + 16384); SB0;
  AISS8(64); SB0;  // A(1)
  asm volatile("s_waitcnt vmcnt(8)" ::: "memory");  // drain B(0),B(1)
  asm volatile("s_waitcnt lgkmcnt(0)" ::: "memory");
  BAR;
  SB0;

#define ITER(M, RA, RB, SC, SD)                                           \
  {                                                                       \
    const int ktB2 = (2 * it + 2) * 64;                                   \
    const int ktB3 = (2 * it + 3) * 64;                                   \
    const char* pBa = ldsc + 65536 + (RA) * 32768 + bOff;                 \
    const char* pBb = ldsc + 65536 + (RB) * 32768 + bOff;                 \
    /* P1: buf0.A/B[RA] kk0; STG B(j+2)->SC; CVT st->buf1.A(j+1); AISS */ \
    LDA8(p0A, swz0); LDB2(pBa, 0, swz0);                                  \
    if (M == 0) {                                                         \
      STG(bS0, bS1, ktB2, 65536 + (SC) * 32768);                          \
      STG(bS2, bS3, ktB2, 65536 + (SC) * 32768 + 16384);                  \
    }                                                                     \
    CVT8(32768);                                                          \
    SB0;                                                                  \
    if (M == 0) { AISS8(ktB2); SB0; }                                     \
    mfma16b<0>(acc, A8, Bf);                                              \
    LDB2(pBa, 4096, swz0);                                                \
    mfma16b<2>(acc, A8, Bf);                                              \
    /* P2: kk1; end: publish P1 LDS writes */                             \
    LDA8(p0A, swz1); LDB2(pBa, 0, swz1);                                  \
    mfma16b<0>(acc, A8, Bf);                                              \
    LDB2(pBa, 4096, swz1);                                                \
    mfma16b<2>(acc, A8, Bf);                                              \
    SB0;                                                                  \
    asm volatile("s_waitcnt lgkmcnt(0)" ::: "memory");                    \
    BAR; SB0;                                                             \
    /* P3: buf1.A/B[RB] kk0; STG B(j+3)->SD; CVT st->buf0.A(j+2); AISS */ \
    LDA8(p1A, swz0); LDB2(pBb, 0, swz0);                                  \
    if (M == 0) {                                                         \
      STG(bS0, bS1, ktB3, 65536 + (SD) * 32768);                          \
      STG(bS2, bS3, ktB3, 65536 + (SD) * 32768 + 16384);                  \
      CVT8(0);                                                            \
      SB0;                                                                \
      AISS8(ktB3);                                                        \
      SB0;                                                                \
    }                                                                     \
    mfma16b<0>(acc, A8, Bf);                                              \
    LDB2(pBb, 4096, swz0);                                                \
    mfma16b<2>(acc, A8, Bf);                                              \
    /* P4: kk1; end: publish P3 LDS writes */                             \
    LDA8(p1A, swz1); LDB2(pBb, 0, swz1);                                  \
    mfma16b<0>(acc, A8, Bf);                                              \
    LDB2(pBb, 4096, swz1);                                                \
    mfma16b<2>(acc, A8, Bf);                                              \
    if (M == 0) {                                                         \
      SB0;                                                                \
      asm volatile("s_waitcnt lgkmcnt(0)" ::: "memory");                  \
      BAR; SB0;                                                           \
    }                                                                     \
  }

#pragma unroll 1
  for (int g = 0; g < 2; ++g) {
    { const int it = 3 * g;     ITER(0, 0, 1, 2, 0) }
    { const int it = 3 * g + 1; ITER(0, 2, 0, 1, 2) }
    { const int it = 3 * g + 2; ITER(0, 1, 2, 0, 1) }
  }
  { const int it = 6; ITER(0, 0, 1, 2, 0) }
  { const int it = 7; ITER(1, 2, 0, 1, 2) }
#undef ITER
#undef STG
#undef AISS8
#undef CVTPAIR
#undef CVT8
#undef LDA8
#undef LDB2
#undef SB0
#undef BAR

  // ---- epilogue: C/D layout col=lane&15, row=(lane>>4)*4+r ----
#pragma unroll
  for (int fi = 0; fi < 8; ++fi) {
#pragma unroll
    for (int fj = 0; fj < 4; ++fj) {
      int n = bn * 256 + wn * 64 + fj * 16 + lm;
      float bv = bias[n];
#pragma unroll
      for (int r = 0; r < 4; ++r) {
        size_t m = bm * 256 + wm * 128 + fi * 16 + ((lane >> 4) * 4) + r;
        Cg[m * 1024 + n] = f2bf(acc[fi][fj][r] + bv);
      }
    }
  }
}

// ---------------- 128x128 gload_lds GEMM (Q/O; verified) -------------------
template <typename TOUT>
__global__ __launch_bounds__(256) void gemm_lds(const ushort* __restrict__ Ag,
                                                const ushort* __restrict__ Wg,
                                                const float* __restrict__ bias,
                                                TOUT* __restrict__ Cg) {
  constexpr int K = 1024;
  __shared__ ushort lA[128 * 64];
  __shared__ ushort lB[128 * 64];
  const int tid = threadIdx.x;
  const int lane = tid & 63;
  const int wave = tid >> 6;
  const int wr = (wave >> 1) * 64;
  const int wc = (wave & 1) * 64;
  const int d = blockIdx.x;
  const int bn = (d >> 3) & 7;
  const size_t bm = (size_t)(d & 7) * (gridDim.x >> 6) + (d >> 6);

  const ushort* aB = Ag + bm * 128 * K;
  const ushort* bB = Wg + (size_t)bn * 128 * K;
  const int srow = wave * 32 + (lane >> 3);
  const int scol = ((lane & 7) ^ (lane >> 3)) * 8;
  char* lAc = (char*)lA;
  char* lBc = (char*)lB;

  f32x4 acc[4][4] = {};

  for (int kt = 0; kt < K; kt += 64) {
    __syncthreads();
#pragma unroll
    for (int c = 0; c < 4; ++c) {
      __builtin_amdgcn_global_load_lds(
          (gvp)(aB + (size_t)(srow + c * 8) * K + kt + scol),
          (lvp)(lAc + wave * 4096 + c * 1024), 16, 0, 0);
      __builtin_amdgcn_global_load_lds(
          (gvp)(bB + (size_t)(srow + c * 8) * K + kt + scol),
          (lvp)(lBc + wave * 4096 + c * 1024), 16, 0, 0);
    }
    __syncthreads();
#pragma unroll
    for (int kk = 0; kk < 2; ++kk) {
      bf16x8 af[4], bg[4];
#pragma unroll
      for (int fi = 0; fi < 4; ++fi) {
        int r = wr + fi * 16 + (lane & 15);
        int byte = (r * 128 + kk * 64 + ((lane >> 4) * 16)) ^ ((r & 7) << 4);
        af[fi] = *reinterpret_cast<const bf16x8*>(lAc + byte);
      }
#pragma unroll
      for (int fj = 0; fj < 4; ++fj) {
        int r = wc + fj * 16 + (lane & 15);
        int byte = (r * 128 + kk * 64 + ((lane >> 4) * 16)) ^ ((r & 7) << 4);
        bg[fj] = *reinterpret_cast<const bf16x8*>(lBc + byte);
      }
#pragma unroll
      for (int fi = 0; fi < 4; ++fi)
#pragma unroll
        for (int fj = 0; fj < 4; ++fj)
          acc[fi][fj] = __builtin_amdgcn_mfma_f32_16x16x32_bf16(af[fi], bg[fj],
                                                                acc[fi][fj], 0, 0, 0);
    }
  }
#pragma unroll
  for (int fi = 0; fi < 4; ++fi) {
#pragma unroll
    for (int fj = 0; fj < 4; ++fj) {
      int n = bn * 128 + wc + fj * 16 + (lane & 15);
      float bv = bias[n];
#pragma unroll
      for (int r = 0; r < 4; ++r) {
        size_t m = bm * 128 + wr + fi * 16 + ((lane >> 4) * 4) + r;
        float val = acc[fi][fj][r] + bv;
        if constexpr (sizeof(TOUT) == 2)
          reinterpret_cast<ushort*>(Cg)[m * 1024 + n] = f2bf(val);
        else
          reinterpret_cast<float*>(Cg)[m * 1024 + n] = val;
      }
    }
  }
}

// ------------- reg-staged GEMM (fp32 A): fallback path only ---------------
template <typename TIN, typename TOUT>
__global__ __launch_bounds__(256) void gemm_bias(const TIN* __restrict__ Ag,
                                                 const float* __restrict__ Wg,
                                                 const float* __restrict__ bias,
                                                 TOUT* __restrict__ Cg) {
  constexpr int K = 1024;
  __shared__ char lA[128 * 64 * 2];
  __shared__ char lB[128 * 64 * 2];
  const int tid = threadIdx.x;
  const int lane = tid & 63;
  const int wave = tid >> 6;
  const int wr = (wave >> 1) * 64;
  const int wc = (wave & 1) * 64;
  const int bn = blockIdx.x;
  const size_t bm = blockIdx.y;

  const TIN* aBase = Ag + bm * 128 * K;
  const float* bBase = Wg + (size_t)bn * 128 * K;

  f32x4 acc[4][4] = {};

  for (int kt = 0; kt < K; kt += 64) {
    __syncthreads();
    if constexpr (sizeof(TIN) == 4) {
#pragma unroll
      for (int i = 0; i < 8; ++i) {
        int f = tid + i * 256;
        int row = f >> 4, c4 = f & 15;
        const float4 v = *reinterpret_cast<const float4*>(
            reinterpret_cast<const float*>(aBase) + (size_t)row * K + kt + c4 * 4);
        ushort4 pk;
        pk.x = f2bf(v.x); pk.y = f2bf(v.y); pk.z = f2bf(v.z); pk.w = f2bf(v.w);
        int byte = (row * 128 + c4 * 8) ^ ((row & 7) << 4);
        *reinterpret_cast<ushort4*>(lA + byte) = pk;
      }
    } else {
#pragma unroll
      for (int i = 0; i < 4; ++i) {
        int f = tid + i * 256;
        int row = f >> 3, c8 = f & 7;
        int4 v = *reinterpret_cast<const int4*>(
            reinterpret_cast<const ushort*>(aBase) + (size_t)row * K + kt + c8 * 8);
        int byte = (row * 128 + c8 * 16) ^ ((row & 7) << 4);
        *reinterpret_cast<int4*>(lA + byte) = v;
      }
    }
#pragma unroll
    for (int i = 0; i < 8; ++i) {
      int f = tid + i * 256;
      int row = f >> 4, c4 = f & 15;
      const float4 v =
          *reinterpret_cast<const float4*>(bBase + (size_t)row * K + kt + c4 * 4);
      ushort4 pk;
      pk.x = f2bf(v.x); pk.y = f2bf(v.y); pk.z = f2bf(v.z); pk.w = f2bf(v.w);
      int byte = (row * 128 + c4 * 8) ^ ((row & 7) << 4);
      *reinterpret_cast<ushort4*>(lB + byte) = pk;
    }
    __syncthreads();
#pragma unroll
    for (int kk = 0; kk < 2; ++kk) {
      bf16x8 af[4], bg[4];
#pragma unroll
      for (int fi = 0; fi < 4; ++fi) {
        int r = wr + fi * 16 + (lane & 15);
        int byte = (r * 128 + kk * 64 + ((lane >> 4) * 16)) ^ ((r & 7) << 4);
        af[fi] = *reinterpret_cast<const bf16x8*>(lA + byte);
      }
#pragma unroll
      for (int fj = 0; fj < 4; ++fj) {
        int r = wc + fj * 16 + (lane & 15);
        int byte = (r * 128 + kk * 64 + ((lane >> 4) * 16)) ^ ((r & 7) << 4);
        bg[fj] = *reinterpret_cast<const bf16x8*>(lB + byte);
      }
#pragma unroll
      for (int fi = 0; fi < 4; ++fi)
#pragma unroll
        for (int fj = 0; fj < 4; ++fj)
          acc[fi][fj] =
              __builtin_amdgcn_mfma_f32_16x16x32_bf16(af[fi], bg[fj], acc[fi][fj], 0, 0, 0);
    }
  }
#pragma unroll
  for (int fi = 0; fi < 4; ++fi) {
#pragma unroll
    for (int fj = 0; fj < 4; ++fj) {
      int n = bn * 128 + wc + fj * 16 + (lane & 15);
      float bv = bias[n];
#pragma unroll
      for (int r = 0; r < 4; ++r) {
        size_t m = bm * 128 + wr + fi * 16 + ((lane >> 4) * 4) + r;
        float val = acc[fi][fj][r] + bv;
        if constexpr (sizeof(TOUT) == 2)
          reinterpret_cast<ushort*>(Cg)[m * 1024 + n] = f2bf(val);
        else
          reinterpret_cast<float*>(Cg)[m * 1024 + n] = val;
      }
    }
  }
}

// ---------------- attention: one block per (b,s'), head-axis softmax ------
__global__ __launch_bounds__(512) void attn_kernel(const ushort* __restrict__ Q,
                                                   const ushort* __restrict__ Kl,
                                                   const ushort* __restrict__ Vl,
                                                   ushort* __restrict__ Aout) {
  const int bs = blockIdx.x;
  const int b = bs >> 11, sp = bs & 2047;
  const int tid = threadIdx.x;
  const int wave = tid >> 6, lane = tid & 63;

  __shared__ ushort qrow[1024];
  __shared__ float sc[16][32];
  __shared__ float attnw[16][32];
  __shared__ float mx[32], rinv[32];

  reinterpret_cast<uint*>(qrow)[tid] =
      reinterpret_cast<const uint*>(Q + (size_t)bs * 1024)[tid];
  __syncthreads();

  const int wp = lane & 31, half = lane >> 5;
#pragma unroll
  for (int hh = 0; hh < 2; ++hh) {
    const int h = wave * 2 + hh;
    const int s_k = h * 128 + (sp >> 4);
    const int w_k = (sp & 15) * 2 + (wp >> 4);
    const ushort* kp =
        Kl + (((size_t)(b * 2048 + s_k) * 32) + w_k) * 1024 + (wp & 15) * 64 + half * 32;
    const ushort* qp = qrow + h * 64 + half * 32;
    float dot = 0.f;
#pragma unroll
    for (int j = 0; j < 32; j += 8) {
      int4 kv = *reinterpret_cast<const int4*>(kp + j);
      int4 qv = *reinterpret_cast<const int4*>(qp + j);
      const ushort* ka = reinterpret_cast<const ushort*>(&kv);
      const ushort* qa = reinterpret_cast<const ushort*>(&qv);
#pragma unroll
      for (int t = 0; t < 8; ++t) dot += bf2f(ka[t]) * bf2f(qa[t]);
    }
    dot += __shfl_xor(dot, 32);
    if (half == 0) sc[h][wp] = dot * 0.125f;
  }
  __syncthreads();
  if (tid < 32) {
    float m = sc[0][tid];
#pragma unroll
    for (int h = 1; h < 16; ++h) m = fmaxf(m, sc[h][tid]);
    float s = 0.f;
#pragma unroll
    for (int h = 0; h < 16; ++h) s += __expf(sc[h][tid] - m);
    mx[tid] = m;
    rinv[tid] = 1.f / s;
  }
  __syncthreads();
  if (lane < 32) {
#pragma unroll
    for (int hh = 0; hh < 2; ++hh) {
      const int h = wave * 2 + hh;
      attnw[h][lane] = __expf(sc[h][lane] - mx[lane]) * rinv[lane];
    }
  }
  __syncthreads();
#pragma unroll
  for (int hh = 0; hh < 2; ++hh) {
    const int h = wave * 2 + hh;
    const int s_k = h * 128 + (sp >> 4);
    const size_t vb = (((size_t)(b * 2048 + s_k) * 32) + (sp & 15) * 2) * 1024;
    float a = 0.f;
#pragma unroll
    for (int w2 = 0; w2 < 32; ++w2) {
      float wgt = attnw[h][w2];
      a += wgt * bf2f(Vl[vb + (size_t)(w2 >> 4) * 1024 + (w2 & 15) * 64 + lane]);
    }
    Aout[(((size_t)(b * 16 + h)) * 2048 + sp) * 64 + lane] = f2bf(a);
  }
}

extern "C" void kernel_launch(void* const* d_in, const int* in_sizes, int n_in,
                              void* d_out, int out_size, void* d_ws, size_t ws_size,
                              hipStream_t stream) {
  const float* q = (const float*)d_in[0];
  const float* k = (const float*)d_in[1];
  const float* v = (const float*)d_in[2];
  const float* Wq = (const float*)d_in[3];
  const float* bq = (const float*)d_in[4];
  const float* Wk = (const float*)d_in[5];
  const float* bk = (const float*)d_in[6];
  const float* Wv = (const float*)d_in[7];
  const float* bv = (const float*)d_in[8];
  const float* Wo = (const float*)d_in[9];
  const float* bo = (const float*)d_in[10];
  float* out = (float*)d_out;

  char* ws = (char*)d_ws;
  const size_t MB = 1u << 20;
  ushort* Qlin = (ushort*)ws;                    // 8 MiB
  ushort* Aws  = (ushort*)(ws + 8 * MB);         // 8 MiB
  ushort* wkbf = (ushort*)(ws + 16 * MB);        // 2 MiB
  ushort* wvbf = (ushort*)(ws + 18 * MB);        // 2 MiB
  ushort* wqbf = (ushort*)(ws + 20 * MB);        // 2 MiB
  ushort* wobf = (ushort*)(ws + 22 * MB);        // 2 MiB
  ushort* qbf  = (ushort*)(ws + 24 * MB);        // 8 MiB
  ushort* Klin = (ushort*)(ws + 32 * MB);        // 256 MiB
  ushort* Vlin = (ushort*)(ws + 288 * MB);       // 256 MiB
  const bool full = ws_size >= 800 * MB;

  if (full) {
    cast4_kernel<<<dim3(512), 256, 0, stream>>>(Wq, Wk, Wv, Wo,
                                                wqbf, wkbf, wvbf, wobf);
    cast_kernel<<<dim3(2048), 256, 0, stream>>>(q, qbf, 4194304L);
    gemm_lds<ushort><<<dim3(256), 256, 0, stream>>>(qbf, wqbf, bq, Qlin);
    gemm_big<<<dim3(2048), 512, 0, stream>>>(k, wkbf, bk, Klin);
    gemm_big<<<dim3(2048), 512, 0, stream>>>(v, wvbf, bv, Vlin);
    attn_kernel<<<dim3(4096), dim3(512), 0, stream>>>(Qlin, Klin, Vlin, Aws);
    gemm_lds<float><<<dim3(256), 256, 0, stream>>>(Aws, wobf, bo, out);
  } else {
    gemm_bias<float, ushort><<<dim3(8, 32), 256, 0, stream>>>(q, Wq, bq, Qlin);
    gemm_bias<float, ushort><<<dim3(8, 1024), 256, 0, stream>>>(k, Wk, bk, Klin);
    gemm_bias<float, ushort><<<dim3(8, 1024), 256, 0, stream>>>(v, Wv, bv, Vlin);
    attn_kernel<<<dim3(4096), dim3(512), 0, stream>>>(Qlin, Klin, Vlin, Aws);
    gemm_bias<ushort, float><<<dim3(8, 32), 256, 0, stream>>>(Aws, Wo, bo, out);
  }
}

// Round 16
// 859.295 us; speedup vs baseline: 2.1890x; 1.0037x over previous
//
#include <hip/hip_runtime.h>
#include <hip/hip_bf16.h>

// B=2, S=2048, W=32, D=1024, H=16, hd=64
// Pipeline (full path):
//   bf16-cast: cast4_kernel (Wq,Wk,Wv,Wo in one launch), q (cast_kernel)
//   K+V GEMM: gemm_big MERGED single launch (4096 blocks; d>>11 selects
//             K or V; per-block body byte-identical to round-15 verified
//             kernel: fused fp32->bf16 A-cast, 3-slot B ring, zero manual
//             vmcnt in loop, 2 sync points/iter). Structural note: seven
//             schedule variants plateau at 380-430us / 27-31% MfmaUtil —
//             acc[8][4]=128 AGPR pins 2 waves/SIMD (any extra loop-carried
//             reg spills, proven r10-12); past this needs an acc-64
//             wave-tile redesign (4 waves/SIMD).
//   Q/O GEMM: gemm_lds (128x128)
//   attn: per (b,s') head-softmax gather-attention -> A (4096x1024 bf16)
//   out  = A@Wo^T+bo (fp32)

#define DEVI __device__ __forceinline__

typedef __attribute__((ext_vector_type(8))) short bf16x8;
typedef __attribute__((ext_vector_type(4))) float f32x4;
typedef const __attribute__((address_space(1))) void* gvp;
typedef __attribute__((address_space(3))) void* lvp;

DEVI ushort f2bf(float f) {
  uint u = __float_as_uint(f);
  u = u + 0x7fffu + ((u >> 16) & 1u);
  return (ushort)(u >> 16);
}
DEVI float bf2f(ushort u) { return __uint_as_float(((uint)u) << 16); }

// ---------------- elementwise fp32 -> bf16 cast (RNE), 8 elems/thread ----
__global__ __launch_bounds__(256) void cast_kernel(const float* __restrict__ in,
                                                   ushort* __restrict__ out,
                                                   long n) {
  long i = ((long)blockIdx.x * 256 + threadIdx.x) * 8;
  const long stride = (long)gridDim.x * 256 * 8;
  for (; i < n; i += stride) {
    float4 a = *reinterpret_cast<const float4*>(in + i);
    float4 b = *reinterpret_cast<const float4*>(in + i + 4);
    ushort o[8];
    o[0] = f2bf(a.x); o[1] = f2bf(a.y); o[2] = f2bf(a.z); o[3] = f2bf(a.w);
    o[4] = f2bf(b.x); o[5] = f2bf(b.y); o[6] = f2bf(b.z); o[7] = f2bf(b.w);
    *reinterpret_cast<int4*>(out + i) = *reinterpret_cast<const int4*>(o);
  }
}

// ---- 4 weight matrices (1M fp32 each) in ONE launch: saves 3 launches ----
__global__ __launch_bounds__(256) void cast4_kernel(const float* __restrict__ i0,
                                                    const float* __restrict__ i1,
                                                    const float* __restrict__ i2,
                                                    const float* __restrict__ i3,
                                                    ushort* __restrict__ o0,
                                                    ushort* __restrict__ o1,
                                                    ushort* __restrict__ o2,
                                                    ushort* __restrict__ o3) {
  const long n = 1048576L;
  long i = ((long)blockIdx.x * 256 + threadIdx.x) * 8;
  const long stride = (long)gridDim.x * 256 * 8;
  for (; i < n; i += stride) {
#pragma unroll
    for (int m = 0; m < 4; ++m) {
      const float* in = (m == 0) ? i0 : (m == 1) ? i1 : (m == 2) ? i2 : i3;
      ushort* out = (m == 0) ? o0 : (m == 1) ? o1 : (m == 2) ? o2 : o3;
      float4 a = *reinterpret_cast<const float4*>(in + i);
      float4 b = *reinterpret_cast<const float4*>(in + i + 4);
      ushort o[8];
      o[0] = f2bf(a.x); o[1] = f2bf(a.y); o[2] = f2bf(a.z); o[3] = f2bf(a.w);
      o[4] = f2bf(b.x); o[5] = f2bf(b.y); o[6] = f2bf(b.z); o[7] = f2bf(b.w);
      *reinterpret_cast<int4*>(out + i) = *reinterpret_cast<const int4*>(o);
    }
  }
}

// ---------------- fused-cast B-ring-3 GEMM, merged K+V --------------------
// C = A(fp32) @ W(bf16)^T + bias, bf16 out. Tile 256x256, BK=64, 16 K-tiles,
// 8 iters x 2 tiles. LDS 160K: buf0.A @0 (32K), buf1.A @32K, B ring slots
// 0/1/2 @ 64K+s*32K. Row = 128B = 8 chunks of 16B; stored chunk p of row r
// holds source chunk p^(r&7); fragment read swz ((kk*4+q)^(lm&7))*16.
// grid = 4096: d>>11 selects the (A,W,bias,C) quad (K or V); block body
// byte-identical to the round-15 verified kernel.
template <int FJ0>
DEVI void mfma16b(f32x4 (&acc)[8][4], const bf16x8 (&A)[8], const bf16x8 (&B)[2]) {
  __builtin_amdgcn_s_setprio(1);
#pragma unroll
  for (int fi = 0; fi < 8; ++fi)
#pragma unroll
    for (int j = 0; j < 2; ++j)
      acc[fi][FJ0 + j] = __builtin_amdgcn_mfma_f32_16x16x32_bf16(
          A[fi], B[j], acc[fi][FJ0 + j], 0, 0, 0);
  __builtin_amdgcn_s_setprio(0);
}

__global__ __launch_bounds__(512)
__attribute__((amdgpu_waves_per_eu(2, 2)))
void gemm_big(const float* __restrict__ A0, const ushort* __restrict__ W0,
              const float* __restrict__ b0, ushort* __restrict__ C0,
              const float* __restrict__ A1, const ushort* __restrict__ W1,
              const float* __restrict__ b1, ushort* __restrict__ C1) {
  constexpr int K = 1024;
  __shared__ char lds[163840];
  const int tid = threadIdx.x;
  const int lane = tid & 63;
  const int wave = tid >> 6;
  const int wm = wave >> 2;
  const int wn = wave & 3;
  const int half_sel = blockIdx.x >> 11;      // 0 = K quad, 1 = V quad
  const int d = blockIdx.x & 2047;            // block id within the half
  const float* Ag = half_sel ? A1 : A0;
  const ushort* Wg = half_sel ? W1 : W0;
  const float* bias = half_sel ? b1 : b0;
  ushort* Cg = half_sel ? C1 : C0;
  const int bn = (d >> 3) & 3;
  const size_t bm = (size_t)(d & 7) * 64 + (d >> 5);  // 2048/32 = 64 per XCD

  const ushort* bB = Wg + (size_t)bn * 256 * K;

  const int r0 = tid >> 3;
  const int c0 = (tid & 7) ^ (r0 & 7);
  const float* pR0 = Ag + bm * 256 * K + (size_t)r0 * K + c0 * 8;
  const float* pR1 = pR0 + 64 * K;
  const ushort* bS0 = bB + (size_t)r0 * K + c0 * 8;
  const ushort* bS1 = bB + (size_t)(r0 + 64) * K + c0 * 8;
  const ushort* bS2 = bB + (size_t)(r0 + 128) * K + c0 * 8;
  const ushort* bS3 = bB + (size_t)(r0 + 192) * K + c0 * 8;

  const int lm = lane & 15;
  const int q = lane >> 4;
  const int rowB = lm * 128;
  const int swz0 = (q ^ (lm & 7)) * 16;
  const int swz1 = ((4 + q) ^ (lm & 7)) * 16;
  const char* ldsc = (const char*)lds;
  const char* p0A = ldsc + wm * 16384 + rowB;
  const char* p1A = p0A + 32768;
  const int bOff = (wn >> 1) * 16384 + (wn & 1) * 8192 + rowB;

  f32x4 acc[8][4] = {};
  bf16x8 A8[8];
  bf16x8 Bf[2];
  float4 st[8];  // single shared staging set (intra-iteration liveness only)

#define SB0 __builtin_amdgcn_sched_barrier(0)
#define BAR __builtin_amdgcn_s_barrier()
#define STG(p0, p1, ktE, ldsOff)                                                 \
  {                                                                              \
    __builtin_amdgcn_global_load_lds((gvp)((p0) + (ktE)),                        \
                                     (lvp)(lds + (ldsOff) + tid * 16), 16, 0, 0);\
    __builtin_amdgcn_global_load_lds((gvp)((p1) + (ktE)),                        \
                                     (lvp)(lds + (ldsOff) + 8192 + tid * 16),    \
                                     16, 0, 0);                                  \
  }
#define AISS8(off)                                                      \
  {                                                                     \
    st[0] = *reinterpret_cast<const float4*>(pR0 + (off));              \
    st[1] = *reinterpret_cast<const float4*>(pR0 + (off) + 4);          \
    st[2] = *reinterpret_cast<const float4*>(pR1 + (off));              \
    st[3] = *reinterpret_cast<const float4*>(pR1 + (off) + 4);          \
    st[4] = *reinterpret_cast<const float4*>(pR0 + 131072 + (off));     \
    st[5] = *reinterpret_cast<const float4*>(pR0 + 131072 + (off) + 4); \
    st[6] = *reinterpret_cast<const float4*>(pR1 + 131072 + (off));     \
    st[7] = *reinterpret_cast<const float4*>(pR1 + 131072 + (off) + 4); \
  }
#define CVTPAIR(v0, v1, dstoff)                                              \
  {                                                                          \
    uint w0, w1, w2, w3;                                                     \
    asm("v_cvt_pk_bf16_f32 %0,%1,%2" : "=v"(w0) : "v"((v0).x), "v"((v0).y)); \
    asm("v_cvt_pk_bf16_f32 %0,%1,%2" : "=v"(w1) : "v"((v0).z), "v"((v0).w)); \
    asm("v_cvt_pk_bf16_f32 %0,%1,%2" : "=v"(w2) : "v"((v1).x), "v"((v1).y)); \
    asm("v_cvt_pk_bf16_f32 %0,%1,%2" : "=v"(w3) : "v"((v1).z), "v"((v1).w)); \
    *reinterpret_cast<uint4*>(lds + (dstoff) + tid * 16) =                   \
        make_uint4(w0, w1, w2, w3);                                          \
  }
#define CVT8(base)                          \
  {                                         \
    CVTPAIR(st[0], st[1], (base));          \
    CVTPAIR(st[2], st[3], (base) + 8192);   \
    CVTPAIR(st[4], st[5], (base) + 16384);  \
    CVTPAIR(st[6], st[7], (base) + 24576);  \
  }
#define LDA8(p, swz)                                                       \
  _Pragma("unroll") for (int i_ = 0; i_ < 8; ++i_) {                       \
    A8[i_] = *reinterpret_cast<const bf16x8*>((p) + i_ * 2048 + (swz));    \
  }
#define LDB2(p, fjb, swz)                                                  \
  {                                                                        \
    Bf[0] = *reinterpret_cast<const bf16x8*>((p) + (fjb) + (swz));         \
    Bf[1] = *reinterpret_cast<const bf16x8*>((p) + (fjb) + 2048 + (swz));  \
  }

  // ---- prologue: A(0) cvt -> buf0.A; B(0)->slot0, B(1)->slot1;
  // AISS A(1) left in flight (drained by it0-P1's CVT).
  AISS8(0); SB0;
  CVT8(0);  // auto-drain; writes buf0.A(0)
  SB0;
  STG(bS0, bS1, 0, 65536); STG(bS2, bS3, 0, 65536 + 16384); SB0;
  STG(bS0, bS1, 64, 98304); STG(bS2, bS3, 64, 98304 + 16384); SB0;
  AISS8(64); SB0;  // A(1)
  asm volatile("s_waitcnt vmcnt(8)" ::: "memory");  // drain B(0),B(1)
  asm volatile("s_waitcnt lgkmcnt(0)" ::: "memory");
  BAR;
  SB0;

#define ITER(M, RA, RB, SC, SD)                                           \
  {                                                                       \
    const int ktB2 = (2 * it + 2) * 64;                                   \
    const int ktB3 = (2 * it + 3) * 64;                                   \
    const char* pBa = ldsc + 65536 + (RA) * 32768 + bOff;                 \
    const char* pBb = ldsc + 65536 + (RB) * 32768 + bOff;                 \
    /* P1: buf0.A/B[RA] kk0; STG B(j+2)->SC; CVT st->buf1.A(j+1); AISS */ \
    LDA8(p0A, swz0); LDB2(pBa, 0, swz0);                                  \
    if (M == 0) {                                                         \
      STG(bS0, bS1, ktB2, 65536 + (SC) * 32768);                          \
      STG(bS2, bS3, ktB2, 65536 + (SC) * 32768 + 16384);                  \
    }                                                                     \
    CVT8(32768);                                                          \
    SB0;                                                                  \
    if (M == 0) { AISS8(ktB2); SB0; }                                     \
    mfma16b<0>(acc, A8, Bf);                                              \
    LDB2(pBa, 4096, swz0);                                                \
    mfma16b<2>(acc, A8, Bf);                                              \
    /* P2: kk1; end: publish P1 LDS writes */                             \
    LDA8(p0A, swz1); LDB2(pBa, 0, swz1);                                  \
    mfma16b<0>(acc, A8, Bf);                                              \
    LDB2(pBa, 4096, swz1);                                                \
    mfma16b<2>(acc, A8, Bf);                                              \
    SB0;                                                                  \
    asm volatile("s_waitcnt lgkmcnt(0)" ::: "memory");                    \
    BAR; SB0;                                                             \
    /* P3: buf1.A/B[RB] kk0; STG B(j+3)->SD; CVT st->buf0.A(j+2); AISS */ \
    LDA8(p1A, swz0); LDB2(pBb, 0, swz0);                                  \
    if (M == 0) {                                                         \
      STG(bS0, bS1, ktB3, 65536 + (SD) * 32768);                          \
      STG(bS2, bS3, ktB3, 65536 + (SD) * 32768 + 16384);                  \
      CVT8(0);                                                            \
      SB0;                                                                \
      AISS8(ktB3);                                                        \
      SB0;                                                                \
    }                                                                     \
    mfma16b<0>(acc, A8, Bf);                                              \
    LDB2(pBb, 4096, swz0);                                                \
    mfma16b<2>(acc, A8, Bf);                                              \
    /* P4: kk1; end: publish P3 LDS writes */                             \
    LDA8(p1A, swz1); LDB2(pBb, 0, swz1);                                  \
    mfma16b<0>(acc, A8, Bf);                                              \
    LDB2(pBb, 4096, swz1);                                                \
    mfma16b<2>(acc, A8, Bf);                                              \
    if (M == 0) {                                                         \
      SB0;                                                                \
      asm volatile("s_waitcnt lgkmcnt(0)" ::: "memory");                  \
      BAR; SB0;                                                           \
    }                                                                     \
  }

#pragma unroll 1
  for (int g = 0; g < 2; ++g) {
    { const int it = 3 * g;     ITER(0, 0, 1, 2, 0) }
    { const int it = 3 * g + 1; ITER(0, 2, 0, 1, 2) }
    { const int it = 3 * g + 2; ITER(0, 1, 2, 0, 1) }
  }
  { const int it = 6; ITER(0, 0, 1, 2, 0) }
  { const int it = 7; ITER(1, 2, 0, 1, 2) }
#undef ITER
#undef STG
#undef AISS8
#undef CVTPAIR
#undef CVT8
#undef LDA8
#undef LDB2
#undef SB0
#undef BAR

  // ---- epilogue: C/D layout col=lane&15, row=(lane>>4)*4+r ----
#pragma unroll
  for (int fi = 0; fi < 8; ++fi) {
#pragma unroll
    for (int fj = 0; fj < 4; ++fj) {
      int n = bn * 256 + wn * 64 + fj * 16 + lm;
      float bv = bias[n];
#pragma unroll
      for (int r = 0; r < 4; ++r) {
        size_t m = bm * 256 + wm * 128 + fi * 16 + ((lane >> 4) * 4) + r;
        Cg[m * 1024 + n] = f2bf(acc[fi][fj][r] + bv);
      }
    }
  }
}

// ---------------- 128x128 gload_lds GEMM (Q/O; verified) -------------------
template <typename TOUT>
__global__ __launch_bounds__(256) void gemm_lds(const ushort* __restrict__ Ag,
                                                const ushort* __restrict__ Wg,
                                                const float* __restrict__ bias,
                                                TOUT* __restrict__ Cg) {
  constexpr int K = 1024;
  __shared__ ushort lA[128 * 64];
  __shared__ ushort lB[128 * 64];
  const int tid = threadIdx.x;
  const int lane = tid & 63;
  const int wave = tid >> 6;
  const int wr = (wave >> 1) * 64;
  const int wc = (wave & 1) * 64;
  const int d = blockIdx.x;
  const int bn = (d >> 3) & 7;
  const size_t bm = (size_t)(d & 7) * (gridDim.x >> 6) + (d >> 6);

  const ushort* aB = Ag + bm * 128 * K;
  const ushort* bB = Wg + (size_t)bn * 128 * K;
  const int srow = wave * 32 + (lane >> 3);
  const int scol = ((lane & 7) ^ (lane >> 3)) * 8;
  char* lAc = (char*)lA;
  char* lBc = (char*)lB;

  f32x4 acc[4][4] = {};

  for (int kt = 0; kt < K; kt += 64) {
    __syncthreads();
#pragma unroll
    for (int c = 0; c < 4; ++c) {
      __builtin_amdgcn_global_load_lds(
          (gvp)(aB + (size_t)(srow + c * 8) * K + kt + scol),
          (lvp)(lAc + wave * 4096 + c * 1024), 16, 0, 0);
      __builtin_amdgcn_global_load_lds(
          (gvp)(bB + (size_t)(srow + c * 8) * K + kt + scol),
          (lvp)(lBc + wave * 4096 + c * 1024), 16, 0, 0);
    }
    __syncthreads();
#pragma unroll
    for (int kk = 0; kk < 2; ++kk) {
      bf16x8 af[4], bg[4];
#pragma unroll
      for (int fi = 0; fi < 4; ++fi) {
        int r = wr + fi * 16 + (lane & 15);
        int byte = (r * 128 + kk * 64 + ((lane >> 4) * 16)) ^ ((r & 7) << 4);
        af[fi] = *reinterpret_cast<const bf16x8*>(lAc + byte);
      }
#pragma unroll
      for (int fj = 0; fj < 4; ++fj) {
        int r = wc + fj * 16 + (lane & 15);
        int byte = (r * 128 + kk * 64 + ((lane >> 4) * 16)) ^ ((r & 7) << 4);
        bg[fj] = *reinterpret_cast<const bf16x8*>(lBc + byte);
      }
#pragma unroll
      for (int fi = 0; fi < 4; ++fi)
#pragma unroll
        for (int fj = 0; fj < 4; ++fj)
          acc[fi][fj] = __builtin_amdgcn_mfma_f32_16x16x32_bf16(af[fi], bg[fj],
                                                                acc[fi][fj], 0, 0, 0);
    }
  }
#pragma unroll
  for (int fi = 0; fi < 4; ++fi) {
#pragma unroll
    for (int fj = 0; fj < 4; ++fj) {
      int n = bn * 128 + wc + fj * 16 + (lane & 15);
      float bv = bias[n];
#pragma unroll
      for (int r = 0; r < 4; ++r) {
        size_t m = bm * 128 + wr + fi * 16 + ((lane >> 4) * 4) + r;
        float val = acc[fi][fj][r] + bv;
        if constexpr (sizeof(TOUT) == 2)
          reinterpret_cast<ushort*>(Cg)[m * 1024 + n] = f2bf(val);
        else
          reinterpret_cast<float*>(Cg)[m * 1024 + n] = val;
      }
    }
  }
}

// ------------- reg-staged GEMM (fp32 A): fallback path only ---------------
template <typename TIN, typename TOUT>
__global__ __launch_bounds__(256) void gemm_bias(const TIN* __restrict__ Ag,
                                                 const float* __restrict__ Wg,
                                                 const float* __restrict__ bias,
                                                 TOUT* __restrict__ Cg) {
  constexpr int K = 1024;
  __shared__ char lA[128 * 64 * 2];
  __shared__ char lB[128 * 64 * 2];
  const int tid = threadIdx.x;
  const int lane = tid & 63;
  const int wave = tid >> 6;
  const int wr = (wave >> 1) * 64;
  const int wc = (wave & 1) * 64;
  const int bn = blockIdx.x;
  const size_t bm = blockIdx.y;

  const TIN* aBase = Ag + bm * 128 * K;
  const float* bBase = Wg + (size_t)bn * 128 * K;

  f32x4 acc[4][4] = {};

  for (int kt = 0; kt < K; kt += 64) {
    __syncthreads();
    if constexpr (sizeof(TIN) == 4) {
#pragma unroll
      for (int i = 0; i < 8; ++i) {
        int f = tid + i * 256;
        int row = f >> 4, c4 = f & 15;
        const float4 v = *reinterpret_cast<const float4*>(
            reinterpret_cast<const float*>(aBase) + (size_t)row * K + kt + c4 * 4);
        ushort4 pk;
        pk.x = f2bf(v.x); pk.y = f2bf(v.y); pk.z = f2bf(v.z); pk.w = f2bf(v.w);
        int byte = (row * 128 + c4 * 8) ^ ((row & 7) << 4);
        *reinterpret_cast<ushort4*>(lA + byte) = pk;
      }
    } else {
#pragma unroll
      for (int i = 0; i < 4; ++i) {
        int f = tid + i * 256;
        int row = f >> 3, c8 = f & 7;
        int4 v = *reinterpret_cast<const int4*>(
            reinterpret_cast<const ushort*>(aBase) + (size_t)row * K + kt + c8 * 8);
        int byte = (row * 128 + c8 * 16) ^ ((row & 7) << 4);
        *reinterpret_cast<int4*>(lA + byte) = v;
      }
    }
#pragma unroll
    for (int i = 0; i < 8; ++i) {
      int f = tid + i * 256;
      int row = f >> 4, c4 = f & 15;
      const float4 v =
          *reinterpret_cast<const float4*>(bBase + (size_t)row * K + kt + c4 * 4);
      ushort4 pk;
      pk.x = f2bf(v.x); pk.y = f2bf(v.y); pk.z = f2bf(v.z); pk.w = f2bf(v.w);
      int byte = (row * 128 + c4 * 8) ^ ((row & 7) << 4);
      *reinterpret_cast<ushort4*>(lB + byte) = pk;
    }
    __syncthreads();
#pragma unroll
    for (int kk = 0; kk < 2; ++kk) {
      bf16x8 af[4], bg[4];
#pragma unroll
      for (int fi = 0; fi < 4; ++fi) {
        int r = wr + fi * 16 + (lane & 15);
        int byte = (r * 128 + kk * 64 + ((lane >> 4) * 16)) ^ ((r & 7) << 4);
        af[fi] = *reinterpret_cast<const bf16x8*>(lA + byte);
      }
#pragma unroll
      for (int fj = 0; fj < 4; ++fj) {
        int r = wc + fj * 16 + (lane & 15);
        int byte = (r * 128 + kk * 64 + ((lane >> 4) * 16)) ^ ((r & 7) << 4);
        bg[fj] = *reinterpret_cast<const bf16x8*>(lB + byte);
      }
#pragma unroll
      for (int fi = 0; fi < 4; ++fi)
#pragma unroll
        for (int fj = 0; fj < 4; ++fj)
          acc[fi][fj] =
              __builtin_amdgcn_mfma_f32_16x16x32_bf16(af[fi], bg[fj], acc[fi][fj], 0, 0, 0);
    }
  }
#pragma unroll
  for (int fi = 0; fi < 4; ++fi) {
#pragma unroll
    for (int fj = 0; fj < 4; ++fj) {
      int n = bn * 128 + wc + fj * 16 + (lane & 15);
      float bv = bias[n];
#pragma unroll
      for (int r = 0; r < 4; ++r) {
        size_t m = bm * 128 + wr + fi * 16 + ((lane >> 4) * 4) + r;
        float val = acc[fi][fj][r] + bv;
        if constexpr (sizeof(TOUT) == 2)
          reinterpret_cast<ushort*>(Cg)[m * 1024 + n] = f2bf(val);
        else
          reinterpret_cast<float*>(Cg)[m * 1024 + n] = val;
      }
    }
  }
}

// ---------------- attention: one block per (b,s'), head-axis softmax ------
__global__ __launch_bounds__(512) void attn_kernel(const ushort* __restrict__ Q,
                                                   const ushort* __restrict__ Kl,
                                                   const ushort* __restrict__ Vl,
                                                   ushort* __restrict__ Aout) {
  const int bs = blockIdx.x;
  const int b = bs >> 11, sp = bs & 2047;
  const int tid = threadIdx.x;
  const int wave = tid >> 6, lane = tid & 63;

  __shared__ ushort qrow[1024];
  __shared__ float sc[16][32];
  __shared__ float attnw[16][32];
  __shared__ float mx[32], rinv[32];

  reinterpret_cast<uint*>(qrow)[tid] =
      reinterpret_cast<const uint*>(Q + (size_t)bs * 1024)[tid];
  __syncthreads();

  const int wp = lane & 31, half = lane >> 5;
#pragma unroll
  for (int hh = 0; hh < 2; ++hh) {
    const int h = wave * 2 + hh;
    const int s_k = h * 128 + (sp >> 4);
    const int w_k = (sp & 15) * 2 + (wp >> 4);
    const ushort* kp =
        Kl + (((size_t)(b * 2048 + s_k) * 32) + w_k) * 1024 + (wp & 15) * 64 + half * 32;
    const ushort* qp = qrow + h * 64 + half * 32;
    float dot = 0.f;
#pragma unroll
    for (int j = 0; j < 32; j += 8) {
      int4 kv = *reinterpret_cast<const int4*>(kp + j);
      int4 qv = *reinterpret_cast<const int4*>(qp + j);
      const ushort* ka = reinterpret_cast<const ushort*>(&kv);
      const ushort* qa = reinterpret_cast<const ushort*>(&qv);
#pragma unroll
      for (int t = 0; t < 8; ++t) dot += bf2f(ka[t]) * bf2f(qa[t]);
    }
    dot += __shfl_xor(dot, 32);
    if (half == 0) sc[h][wp] = dot * 0.125f;
  }
  __syncthreads();
  if (tid < 32) {
    float m = sc[0][tid];
#pragma unroll
    for (int h = 1; h < 16; ++h) m = fmaxf(m, sc[h][tid]);
    float s = 0.f;
#pragma unroll
    for (int h = 0; h < 16; ++h) s += __expf(sc[h][tid] - m);
    mx[tid] = m;
    rinv[tid] = 1.f / s;
  }
  __syncthreads();
  if (lane < 32) {
#pragma unroll
    for (int hh = 0; hh < 2; ++hh) {
      const int h = wave * 2 + hh;
      attnw[h][lane] = __expf(sc[h][lane] - mx[lane]) * rinv[lane];
    }
  }
  __syncthreads();
#pragma unroll
  for (int hh = 0; hh < 2; ++hh) {
    const int h = wave * 2 + hh;
    const int s_k = h * 128 + (sp >> 4);
    const size_t vb = (((size_t)(b * 2048 + s_k) * 32) + (sp & 15) * 2) * 1024;
    float a = 0.f;
#pragma unroll
    for (int w2 = 0; w2 < 32; ++w2) {
      float wgt = attnw[h][w2];
      a += wgt * bf2f(Vl[vb + (size_t)(w2 >> 4) * 1024 + (w2 & 15) * 64 + lane]);
    }
    Aout[(((size_t)(b * 16 + h)) * 2048 + sp) * 64 + lane] = f2bf(a);
  }
}

extern "C" void kernel_launch(void* const* d_in, const int* in_sizes, int n_in,
                              void* d_out, int out_size, void* d_ws, size_t ws_size,
                              hipStream_t stream) {
  const float* q = (const float*)d_in[0];
  const float* k = (const float*)d_in[1];
  const float* v = (const float*)d_in[2];
  const float* Wq = (const float*)d_in[3];
  const float* bq = (const float*)d_in[4];
  const float* Wk = (const float*)d_in[5];
  const float* bk = (const float*)d_in[6];
  const float* Wv = (const float*)d_in[7];
  const float* bv = (const float*)d_in[8];
  const float* Wo = (const float*)d_in[9];
  const float* bo = (const float*)d_in[10];
  float* out = (float*)d_out;

  char* ws = (char*)d_ws;
  const size_t MB = 1u << 20;
  ushort* Qlin = (ushort*)ws;                    // 8 MiB
  ushort* Aws  = (ushort*)(ws + 8 * MB);         // 8 MiB
  ushort* wkbf = (ushort*)(ws + 16 * MB);        // 2 MiB
  ushort* wvbf = (ushort*)(ws + 18 * MB);        // 2 MiB
  ushort* wqbf = (ushort*)(ws + 20 * MB);        // 2 MiB
  ushort* wobf = (ushort*)(ws + 22 * MB);        // 2 MiB
  ushort* qbf  = (ushort*)(ws + 24 * MB);        // 8 MiB
  ushort* Klin = (ushort*)(ws + 32 * MB);        // 256 MiB
  ushort* Vlin = (ushort*)(ws + 288 * MB);       // 256 MiB
  const bool full = ws_size >= 800 * MB;

  if (full) {
    cast4_kernel<<<dim3(512), 256, 0, stream>>>(Wq, Wk, Wv, Wo,
                                                wqbf, wkbf, wvbf, wobf);
    cast_kernel<<<dim3(2048), 256, 0, stream>>>(q, qbf, 4194304L);
    gemm_lds<ushort><<<dim3(256), 256, 0, stream>>>(qbf, wqbf, bq, Qlin);
    // K + V GEMMs merged into one 4096-block launch
    gemm_big<<<dim3(4096), 512, 0, stream>>>(k, wkbf, bk, Klin,
                                             v, wvbf, bv, Vlin);
    attn_kernel<<<dim3(4096), dim3(512), 0, stream>>>(Qlin, Klin, Vlin, Aws);
    gemm_lds<float><<<dim3(256), 256, 0, stream>>>(Aws, wobf, bo, out);
  } else {
    gemm_bias<float, ushort><<<dim3(8, 32), 256, 0, stream>>>(q, Wq, bq, Qlin);
    gemm_bias<float, ushort><<<dim3(8, 1024), 256, 0, stream>>>(k, Wk, bk, Klin);
    gemm_bias<float, ushort><<<dim3(8, 1024), 256, 0, stream>>>(v, Wv, bv, Vlin);
    attn_kernel<<<dim3(4096), dim3(512), 0, stream>>>(Qlin, Klin, Vlin, Aws);
    gemm_bias<ushort, float><<<dim3(8, 32), 256, 0, stream>>>(Aws, Wo, bo, out);
  }
}